// Round 9
// baseline (210.348 us; speedup 1.0000x reference)
//
#include <hip/hip_runtime.h>

typedef __bf16 bf16x8 __attribute__((ext_vector_type(8)));
typedef float f32x4 __attribute__((ext_vector_type(4)));
typedef float f32x16 __attribute__((ext_vector_type(16)));
typedef int i32x2 __attribute__((ext_vector_type(2)));

__device__ __forceinline__ unsigned short f2bf(float f) {
  return __builtin_bit_cast(unsigned short, (__bf16)f);
}
__device__ __forceinline__ float bfu2f(unsigned short b) {
  unsigned int u = ((unsigned int)b) << 16;
  return __builtin_bit_cast(float, u);
}
// fast silu: x * rcp(1+exp(-x)).
__device__ __forceinline__ float silu_f(float x) {
  return x * __builtin_amdgcn_rcpf(1.0f + __expf(-x));
}
__device__ __forceinline__ unsigned pk2(float a, float b) {
  return (unsigned)f2bf(a) | ((unsigned)f2bf(b) << 16);
}

// Stage a tile into LDS via global_load_lds (16B/lane). Logical layout:
// [rows][CPR*8 cols] bf16. Chunk slot s of row r holds SOURCE col block
// s^(r&SWZ); readers fetch block b at slot b^(r&SWZ).
template<int CPR, int NI, int SWZ>
__device__ __forceinline__ void stage16(const __bf16* __restrict__ g, int ld,
                                        __bf16* lds, int wave, int lane) {
#pragma unroll
  for (int t = 0; t < NI; ++t) {
    int cb = (wave * NI + t) * 64;
    int c = cb + lane;
    int row = c / CPR;
    int colb = (c % CPR) ^ (row & SWZ);
    __builtin_amdgcn_global_load_lds(
        (const __attribute__((address_space(1))) unsigned int*)(g + row * ld + colb * 8),
        (__attribute__((address_space(3))) unsigned int*)(lds + cb * 8),
        16, 0, 0);
  }
}

// ---------------- fused prep kernel ----------------
__global__ void k_prep(const float* __restrict__ x, __bf16* __restrict__ nx,
                       const float* __restrict__ ow, __bf16* __restrict__ owb,
                       const float* __restrict__ uvqk, __bf16* __restrict__ uvqkT) {
  int bid = blockIdx.x, tid = threadIdx.x;
  if (bid < 4096) {
    int t = tid & 127;             // position within row
    int r = bid * 2 + (tid >> 7);  // row
    int wave = tid >> 6;           // 0..3 (2 waves per row)
    float4 v = ((const float4*)(x + (size_t)r * 512))[t];
    float s = v.x + v.y + v.z + v.w;
    float ss = v.x * v.x + v.y * v.y + v.z * v.z + v.w * v.w;
#pragma unroll
    for (int o = 32; o > 0; o >>= 1) { s += __shfl_down(s, o); ss += __shfl_down(ss, o); }
    __shared__ float red[4][2];
    if ((tid & 63) == 0) { red[wave][0] = s; red[wave][1] = ss; }
    __syncthreads();
    int rw = (wave >> 1) * 2;
    s = red[rw][0] + red[rw + 1][0];
    ss = red[rw][1] + red[rw + 1][1];
    float mu = s * (1.0f / 512.0f);
    float var = ss * (1.0f / 512.0f) - mu * mu;
    float rs = rsqrtf(var + 1e-6f);
    ushort4 o4;
    o4.x = f2bf((v.x - mu) * rs); o4.y = f2bf((v.y - mu) * rs);
    o4.z = f2bf((v.z - mu) * rs); o4.w = f2bf((v.w - mu) * rs);
    ((ushort4*)(nx + (size_t)r * 512))[t] = o4;
  } else if (bid < 4352) {
    int i = (bid - 4096) * 256 + tid;
    float4 v = ((const float4*)ow)[i];
    ushort4 o4;
    o4.x = f2bf(v.x); o4.y = f2bf(v.y); o4.z = f2bf(v.z); o4.w = f2bf(v.w);
    ((ushort4*)owb)[i] = o4;
  } else {
    __shared__ float tile[32][33];
    int bb = bid - 4352;
    int n0 = (bb & 63) * 32, k0 = (bb >> 6) * 32;
    int tx = tid & 31, ty = tid >> 5;  // 32 x 8
    for (int i = ty; i < 32; i += 8)
      tile[i][tx] = uvqk[(k0 + i) * 2048 + n0 + tx];
    __syncthreads();
    for (int i = ty; i < 32; i += 8)
      uvqkT[(n0 + i) * 512 + k0 + tx] = (__bf16)tile[tx][i];
  }
}

// ---------------- projection GEMM (v11, frozen) ----------------
__global__ __launch_bounds__(256, 2) void k_proj(
    const __bf16* __restrict__ A, const __bf16* __restrict__ Bt,
    __bf16* __restrict__ u, __bf16* __restrict__ qn,
    __bf16* __restrict__ kn, __bf16* __restrict__ vt) {
  __shared__ __bf16 lds[32768];  // 64 KB: A0@0, B0@8192, A1@16384, B1@24576
  int tid = threadIdx.x, wave = tid >> 6, lane = tid & 63;
  int lr = lane & 15, lq = lane >> 4;
  int bn = blockIdx.x, bm = blockIdx.y;
  const __bf16* Ag = A + (size_t)bm * 128 * 512;
  const __bf16* Bg = Bt + (size_t)bn * 128 * 512;
  int wm = (wave >> 1) * 64, wn = (wave & 1) * 64;
  f32x4 acc[4][4] = {};
  stage16<8, 4, 7>(Ag, 512, lds, wave, lane);
  stage16<8, 4, 7>(Bg, 512, lds + 8192, wave, lane);
  asm volatile("s_waitcnt vmcnt(0)" ::: "memory");
  __builtin_amdgcn_sched_barrier(0);
  __builtin_amdgcn_s_barrier();
  __builtin_amdgcn_sched_barrier(0);
  int buf = 0;
  for (int t = 0; t < 8; ++t) {
    if (t + 1 < 8) {
      int nb = buf ^ 1;
      stage16<8, 4, 7>(Ag + (t + 1) * 64, 512, lds + nb * 16384, wave, lane);
      stage16<8, 4, 7>(Bg + (t + 1) * 64, 512, lds + nb * 16384 + 8192, wave, lane);
    }
    const __bf16* As = lds + buf * 16384;
    const __bf16* Bs = lds + buf * 16384 + 8192;
#pragma unroll
    for (int kk = 0; kk < 2; ++kk) {
      int b = kk * 4 + lq;
      bf16x8 a[4], bb[4];
#pragma unroll
      for (int i = 0; i < 4; ++i) {
        int row = wm + i * 16 + lr;
        a[i] = *(const bf16x8*)(As + row * 64 + ((b ^ (row & 7)) * 8));
      }
#pragma unroll
      for (int j = 0; j < 4; ++j) {
        int row = wn + j * 16 + lr;
        bb[j] = *(const bf16x8*)(Bs + row * 64 + ((b ^ (row & 7)) * 8));
      }
#pragma unroll
      for (int i = 0; i < 4; ++i)
#pragma unroll
        for (int j = 0; j < 4; ++j)
          acc[i][j] = __builtin_amdgcn_mfma_f32_16x16x32_bf16(a[i], bb[j], acc[i][j], 0, 0, 0);
    }
    asm volatile("s_waitcnt vmcnt(0)" ::: "memory");
    __builtin_amdgcn_sched_barrier(0);
    __builtin_amdgcn_s_barrier();
    __builtin_amdgcn_sched_barrier(0);
    buf ^= 1;
  }
  int seg = bn >> 2;  // 128-wide block lies entirely in one 512-col segment
  int cb = (bn & 3) * 128 + wn;
  int rb0 = bm * 128 + wm + lq * 4;
  if (seg == 1) {
#pragma unroll
    for (int i = 0; i < 4; ++i) {
      int rb = rb0 + i * 16;
      int b = rb >> 11, n = rb & 2047;
#pragma unroll
      for (int j = 0; j < 4; ++j) {
        int c = cb + j * 16 + lr;
        ushort4 w;
        w.x = f2bf(silu_f(acc[i][j][0]) * (1.0f / 2048.0f));
        w.y = f2bf(silu_f(acc[i][j][1]) * (1.0f / 2048.0f));
        w.z = f2bf(silu_f(acc[i][j][2]) * (1.0f / 2048.0f));
        w.w = f2bf(silu_f(acc[i][j][3]) * (1.0f / 2048.0f));
        *(ushort4*)(vt + ((size_t)(b * 512 + c)) * 2048 + n) = w;
      }
    }
  } else {
    __bf16* dst = (seg == 0) ? u : ((seg == 2) ? qn : kn);
#pragma unroll
    for (int i = 0; i < 4; ++i) {
      int rb = rb0 + i * 16;
#pragma unroll
      for (int j = 0; j < 4; ++j) {
        int c = cb + j * 16 + lr;
#pragma unroll
        for (int rg = 0; rg < 4; ++rg)
          dst[(size_t)(rb + rg) * 512 + c] = (__bf16)silu_f(acc[i][j][rg]);
      }
    }
  }
}

// ---------------- fused causal silu-attention (v10, frozen) ----------------
template<bool DT>
__device__ __forceinline__ void attn_finish(
    const f32x16& s, int m0, int n0, int l31, int lh, int ms, bool natural,
    const __bf16* Vc, f32x16 po[2]) {
  unsigned pk[8];
#pragma unroll
  for (int q = 0; q < 8; ++q) {
    float p01[2];
#pragma unroll
    for (int h = 0; h < 2; ++h) {
      int r = 2 * q + h;
      float xx = s[r];
      float pv = xx * __builtin_amdgcn_rcpf(1.0f + __expf(-xx));
      if (DT) {
        int mrow = m0 + 4 * lh + (r & 3) + 8 * (r >> 2);
        if (mrow > n0 + l31) pv = 0.0f;
      }
      p01[h] = pv;
    }
    pk[q] = pk2(p01[0], p01[1]);
  }
  i32x2 r0 = __builtin_amdgcn_permlane32_swap((int)pk[0], (int)pk[2], false, false);
  i32x2 r1 = __builtin_amdgcn_permlane32_swap((int)pk[1], (int)pk[3], false, false);
  i32x2 r2 = __builtin_amdgcn_permlane32_swap((int)pk[4], (int)pk[6], false, false);
  i32x2 r3 = __builtin_amdgcn_permlane32_swap((int)pk[5], (int)pk[7], false, false);
  union { bf16x8 v; unsigned u[4]; } f0, f1;
  if (natural) {
    f0.u[0] = r0.x; f0.u[2] = r0.y; f0.u[1] = r1.x; f0.u[3] = r1.y;
    f1.u[0] = r2.x; f1.u[2] = r2.y; f1.u[1] = r3.x; f1.u[3] = r3.y;
  } else {
    f0.u[0] = r0.y; f0.u[2] = r0.x; f0.u[1] = r1.y; f0.u[3] = r1.x;
    f1.u[0] = r2.y; f1.u[2] = r2.x; f1.u[1] = r3.y; f1.u[3] = r3.x;
  }
  bf16x8 pf[2] = { f0.v, f1.v };
#pragma unroll
  for (int t2 = 0; t2 < 2; ++t2) {
#pragma unroll
    for (int idl = 0; idl < 2; ++idl) {
      int row = idl * 32 + l31;
      bf16x8 av = *(const bf16x8*)(Vc + row * 64 +
          (((ms * 4 + t2 * 2 + lh) ^ (row & 7)) * 8));
      po[idl] = __builtin_amdgcn_mfma_f32_32x32x16_bf16(av, pf[t2], po[idl], 0, 0, 0);
    }
  }
}

__global__ __launch_bounds__(256, 4) void k_attn(
    const __bf16* __restrict__ qn, const __bf16* __restrict__ kn,
    const __bf16* __restrict__ vt, __bf16* __restrict__ oa,
    __bf16* __restrict__ ob, __bf16* __restrict__ oc) {
  __shared__ __bf16 lds[16384];  // 32 KB
  __bf16* Kb0 = lds;             // [64 m][64 k] 8KB
  __bf16* Kb1 = lds + 4096;
  __bf16* Vb0 = lds + 8192;      // [64 dl][64 m] 8KB
  __bf16* Vb1 = lds + 12288;
  __bf16* bo = lds;              // [128 n][64 dl] 16KB over K bufs (dead at epilogue)

  int bh = blockIdx.x, p = blockIdx.y, z = blockIdx.z;
  int b = bh >> 3, hd = bh & 7;
  int tid = threadIdx.x, wave = tid >> 6, lane = tid & 63;
  int l31 = lane & 31, lh = lane >> 5;
  const __bf16* Kg = kn + (size_t)(b * 2048) * 512 + hd * 64;
  const __bf16* Vg = vt + (size_t)(b * 512 + hd * 64) * 2048;
  __bf16* Oz = (z == 0) ? oa : ((z == 1) ? ob : oc);

  i32x2 pr = __builtin_amdgcn_permlane32_swap(lh ? 10 : 11, lh ? 20 : 21, false, false);
  bool natural = (__builtin_amdgcn_readfirstlane(pr.x) == 11);

  for (int ph = 0; ph < 2; ++ph) {
    int t = ph ? (15 - p) : p;
    int T = 2 * t + 2;             // m-tiles needed for this q-tile
    int mlo = z * T / 3;
    int cnt = (z + 1) * T / 3 - mlo;
    int n0 = t * 128 + wave * 32;  // this wave's first q-row (global)
    if (ph) __syncthreads();       // epilogue LDS reads done before restaging
    const __bf16* Qg = qn + (size_t)(b * 2048 + n0 + l31) * 512 + hd * 64 + lh * 8;
    bf16x8 qf[4];
#pragma unroll
    for (int ks = 0; ks < 4; ++ks) qf[ks] = *(const bf16x8*)(Qg + ks * 16);
    if (cnt > 0) {
      stage16<8, 2, 7>(Kg + (size_t)mlo * 64 * 512, 512, Kb0, wave, lane);
      stage16<8, 2, 7>(Vg + mlo * 64, 2048, Vb0, wave, lane);
    }
    __syncthreads();

    f32x16 po[2] = {};

    for (int i = 0; i < cnt; ++i) {
      int mt = mlo + i;
      const __bf16* Kc = (i & 1) ? Kb1 : Kb0;
      const __bf16* Vc = (i & 1) ? Vb1 : Vb0;
      if (i + 1 < cnt) {
        __bf16* Kn_ = (i & 1) ? Kb0 : Kb1;
        __bf16* Vn_ = (i & 1) ? Vb0 : Vb1;
        stage16<8, 2, 7>(Kg + (size_t)(mt + 1) * 64 * 512, 512, Kn_, wave, lane);
        stage16<8, 2, 7>(Vg + (mt + 1) * 64, 2048, Vn_, wave, lane);
      }
#pragma unroll
      for (int ms = 0; ms < 2; ++ms) {
        int m0 = mt * 64 + ms * 32;       // global first m-row of subtile
        if (m0 > n0) continue;            // fully masked (32-aligned: m0<=n0 iff active)
        f32x16 s = {};
#pragma unroll
        for (int ks = 0; ks < 4; ++ks) {
          int row = ms * 32 + l31;
          bf16x8 ak = *(const bf16x8*)(Kc + row * 64 + (((ks * 2 + lh) ^ (row & 7)) * 8));
          s = __builtin_amdgcn_mfma_f32_32x32x16_bf16(ak, qf[ks], s, 0, 0, 0);
        }
        if (m0 == n0) attn_finish<true>(s, m0, n0, l31, lh, ms, natural, Vc, po);
        else          attn_finish<false>(s, m0, n0, l31, lh, ms, natural, Vc, po);
      }
      __syncthreads();
    }

    // epilogue: pack own accumulators -> xor-swizzled bounce [128 n][64 dl]
    {
      int nrow = wave * 32 + l31;
#pragma unroll
      for (int idl = 0; idl < 2; ++idl) {
#pragma unroll
        for (int g = 0; g < 4; ++g) {
          int dl0 = idl * 32 + g * 8 + lh * 4;
          int addr = nrow * 64 + ((((dl0 >> 3) ^ (nrow & 7)) << 3) | (dl0 & 7));
          ushort4 w;
          w.x = f2bf(po[idl][4 * g + 0]); w.y = f2bf(po[idl][4 * g + 1]);
          w.z = f2bf(po[idl][4 * g + 2]); w.w = f2bf(po[idl][4 * g + 3]);
          *(ushort4*)(bo + addr) = w;
        }
      }
    }
    __syncthreads();
    // coalesced store: Oz[b, t*128+n, hd*64 + c], 64B/thread
    {
      int n = tid >> 1, cc = (tid & 1) * 32;
      __bf16* gdst = Oz + (size_t)(b * 2048 + t * 128 + n) * 512 + hd * 64 + cc;
#pragma unroll
      for (int kk2 = 0; kk2 < 4; ++kk2) {
        int dlb = cc + kk2 * 8;
        int a = n * 64 + (((dlb >> 3) ^ (n & 7)) << 3);
        *(uint4*)(gdst + kk2 * 8) = *(const uint4*)(bo + a);
      }
    }
  }
}

// o_input = u * layer_norm(oa + ob + oc), one block (128 thr) per row (Path B)
__global__ void k_oinput(const __bf16* __restrict__ oa, const __bf16* __restrict__ ob,
                         const __bf16* __restrict__ oc, const __bf16* __restrict__ u,
                         __bf16* __restrict__ oin) {
  int r = blockIdx.x, t = threadIdx.x;
  ushort4 a4 = ((const ushort4*)(oa + (size_t)r * 512))[t];
  ushort4 b4 = ((const ushort4*)(ob + (size_t)r * 512))[t];
  ushort4 c4 = ((const ushort4*)(oc + (size_t)r * 512))[t];
  float a0 = bfu2f(a4.x) + bfu2f(b4.x) + bfu2f(c4.x);
  float a1 = bfu2f(a4.y) + bfu2f(b4.y) + bfu2f(c4.y);
  float a2 = bfu2f(a4.z) + bfu2f(b4.z) + bfu2f(c4.z);
  float a3 = bfu2f(a4.w) + bfu2f(b4.w) + bfu2f(c4.w);
  float s = a0 + a1 + a2 + a3;
  float ss = a0 * a0 + a1 * a1 + a2 * a2 + a3 * a3;
#pragma unroll
  for (int o = 32; o > 0; o >>= 1) { s += __shfl_down(s, o); ss += __shfl_down(ss, o); }
  __shared__ float red[4];
  if ((t & 63) == 0) { red[(t >> 6) * 2] = s; red[(t >> 6) * 2 + 1] = ss; }
  __syncthreads();
  s = red[0] + red[2]; ss = red[1] + red[3];
  float mu = s * (1.0f / 512.0f);
  float var = ss * (1.0f / 512.0f) - mu * mu;
  float rs = rsqrtf(var + 1e-6f);
  ushort4 u4 = ((const ushort4*)(u + (size_t)r * 512))[t];
  ushort4 o4;
  o4.x = f2bf(bfu2f(u4.x) * (a0 - mu) * rs);
  o4.y = f2bf(bfu2f(u4.y) * (a1 - mu) * rs);
  o4.z = f2bf(bfu2f(u4.z) * (a2 - mu) * rs);
  o4.w = f2bf(bfu2f(u4.w) * (a3 - mu) * rs);
  ((ushort4*)(oin + (size_t)r * 512))[t] = o4;
}

// Path B k_out (v11): out = o_in @ ow^T + bias + x. 64x128 tile, 2-phase dbuf.
__global__ __launch_bounds__(256, 3) void k_out(
    const __bf16* __restrict__ A, const __bf16* __restrict__ Bt,
    const float* __restrict__ bias, const float* __restrict__ x,
    float* __restrict__ out) {
  __shared__ __bf16 lds[24576];  // 48 KB: A0@0, B0@4096, A1@12288, B1@16384
  int tid = threadIdx.x, wave = tid >> 6, lane = tid & 63;
  int lr = lane & 15, lq = lane >> 4;
  int bn = blockIdx.x, bm = blockIdx.y;
  const __bf16* Ag = A + (size_t)bm * 64 * 512;
  const __bf16* Bg = Bt + (size_t)bn * 128 * 512;
  int wm = (wave >> 1) * 32, wn = (wave & 1) * 64;
  f32x4 acc[2][4] = {};
  stage16<8, 2, 7>(Ag, 512, lds, wave, lane);
  stage16<8, 4, 7>(Bg, 512, lds + 4096, wave, lane);
  asm volatile("s_waitcnt vmcnt(0)" ::: "memory");
  __builtin_amdgcn_sched_barrier(0);
  __builtin_amdgcn_s_barrier();
  __builtin_amdgcn_sched_barrier(0);
  int buf = 0;
  for (int t = 0; t < 8; ++t) {
    if (t + 1 < 8) {
      int nb = buf ^ 1;
      stage16<8, 2, 7>(Ag + (t + 1) * 64, 512, lds + nb * 12288, wave, lane);
      stage16<8, 4, 7>(Bg + (t + 1) * 64, 512, lds + nb * 12288 + 4096, wave, lane);
    }
    const __bf16* As = lds + buf * 12288;
    const __bf16* Bs = lds + buf * 12288 + 4096;
#pragma unroll
    for (int kk = 0; kk < 2; ++kk) {
      int b = kk * 4 + lq;
      bf16x8 a[2], bb[4];
#pragma unroll
      for (int i = 0; i < 2; ++i) {
        int row = wm + i * 16 + lr;
        a[i] = *(const bf16x8*)(As + row * 64 + ((b ^ (row & 7)) * 8));
      }
#pragma unroll
      for (int j = 0; j < 4; ++j) {
        int row = wn + j * 16 + lr;
        bb[j] = *(const bf16x8*)(Bs + row * 64 + ((b ^ (row & 7)) * 8));
      }
#pragma unroll
      for (int i = 0; i < 2; ++i)
#pragma unroll
        for (int j = 0; j < 4; ++j)
          acc[i][j] = __builtin_amdgcn_mfma_f32_16x16x32_bf16(a[i], bb[j], acc[i][j], 0, 0, 0);
    }
    asm volatile("s_waitcnt vmcnt(0)" ::: "memory");
    __builtin_amdgcn_sched_barrier(0);
    __builtin_amdgcn_s_barrier();
    __builtin_amdgcn_sched_barrier(0);
    buf ^= 1;
  }
  int cb = bn * 128 + wn;
  int rb0 = bm * 64 + wm + lq * 4;
#pragma unroll
  for (int j = 0; j < 4; ++j) {
    int c = cb + j * 16 + lr;
    float bv = bias[c];
#pragma unroll
    for (int i = 0; i < 2; ++i) {
      int rb = rb0 + i * 16;
#pragma unroll
      for (int rg = 0; rg < 4; ++rg) {
        size_t idx = (size_t)(rb + rg) * 512 + c;
        out[idx] = acc[i][j][rg] + bv + x[idx];
      }
    }
  }
}

// Path A: out = (u*LN(oa+ob+oc)) @ ow^T + bias + x, k_oinput FUSED into the
// GEMM prologue. 32x128 tile; A (normalized, u-gated) built in LDS by the
// block (K=512 == LN axis == A-tile width); B dbuf 2-phase. 64 KB LDS,
// 2 blocks/CU, grid (4, 256).
__global__ __launch_bounds__(256, 2) void k_out_fused(
    const __bf16* __restrict__ oa, const __bf16* __restrict__ ob,
    const __bf16* __restrict__ oc, const __bf16* __restrict__ u,
    const __bf16* __restrict__ Bt, const float* __restrict__ bias,
    const float* __restrict__ x, float* __restrict__ out) {
  __shared__ __bf16 lds[32768];  // A 32KB @0 (8 sub-bufs [32][64]); B0@16384, B1@24576
  int tid = threadIdx.x, wave = tid >> 6, lane = tid & 63;
  int lr = lane & 15, lq = lane >> 4;
  int bn = blockIdx.x, bm = blockIdx.y;
  const __bf16* Bg = Bt + (size_t)bn * 128 * 512;
  int wn = wave * 32;

  // ---- prologue: A = u * LN(oa+ob+oc) for rows [bm*32, bm*32+32) ----
  {
    int r = tid >> 3, q = tid & 7;       // 32 rows x 8 threads/row
    size_t R = (size_t)(bm * 32 + r) * 512;
    float s = 0.f, ss = 0.f;
#pragma unroll
    for (int j = 0; j < 8; ++j) {
      int c = q * 8 + j * 64;
      uint4 a4 = *(const uint4*)(oa + R + c);
      uint4 b4 = *(const uint4*)(ob + R + c);
      uint4 c4 = *(const uint4*)(oc + R + c);
#pragma unroll
      for (int e = 0; e < 4; ++e) {
        unsigned aw = ((const unsigned*)&a4)[e], bw = ((const unsigned*)&b4)[e],
                 cw = ((const unsigned*)&c4)[e];
        float v0 = bfu2f((unsigned short)aw) + bfu2f((unsigned short)bw) + bfu2f((unsigned short)cw);
        float v1 = bfu2f((unsigned short)(aw >> 16)) + bfu2f((unsigned short)(bw >> 16)) + bfu2f((unsigned short)(cw >> 16));
        s += v0 + v1; ss += v0 * v0 + v1 * v1;
      }
    }
    s += __shfl_xor(s, 1); ss += __shfl_xor(ss, 1);
    s += __shfl_xor(s, 2); ss += __shfl_xor(ss, 2);
    s += __shfl_xor(s, 4); ss += __shfl_xor(ss, 4);
    float mu = s * (1.0f / 512.0f);
    float var = ss * (1.0f / 512.0f) - mu * mu;
    float rs = rsqrtf(var + 1e-6f);
#pragma unroll
    for (int j = 0; j < 8; ++j) {
      int c = q * 8 + j * 64;
      uint4 a4 = *(const uint4*)(oa + R + c);
      uint4 b4 = *(const uint4*)(ob + R + c);
      uint4 c4 = *(const uint4*)(oc + R + c);
      uint4 u4 = *(const uint4*)(u + R + c);
      uint4 w;
#pragma unroll
      for (int e = 0; e < 4; ++e) {
        unsigned aw = ((const unsigned*)&a4)[e], bw = ((const unsigned*)&b4)[e],
                 cw = ((const unsigned*)&c4)[e], uw = ((const unsigned*)&u4)[e];
        float v0 = bfu2f((unsigned short)aw) + bfu2f((unsigned short)bw) + bfu2f((unsigned short)cw);
        float v1 = bfu2f((unsigned short)(aw >> 16)) + bfu2f((unsigned short)(bw >> 16)) + bfu2f((unsigned short)(cw >> 16));
        float g0 = bfu2f((unsigned short)uw) * (v0 - mu) * rs;
        float g1 = bfu2f((unsigned short)(uw >> 16)) * (v1 - mu) * rs;
        ((unsigned*)&w)[e] = pk2(g0, g1);
      }
      // swizzled A slot: sub-buffer j, row r, col-block q at slot q^(r&7)
      *(uint4*)(lds + j * 2048 + r * 64 + ((q ^ (r & 7)) * 8)) = w;
    }
  }
  // stage B(0)
  stage16<8, 4, 7>(Bg, 512, lds + 16384, wave, lane);
  __syncthreads();  // drains ds_writes (A) + vm loads (B0)

  f32x4 acc[2][2] = {};
  int buf = 0;
  for (int t = 0; t < 8; ++t) {
    if (t + 1 < 8) {
      int nb = buf ^ 1;
      stage16<8, 4, 7>(Bg + (t + 1) * 64, 512, lds + 16384 + nb * 8192, wave, lane);
    }
    const __bf16* As = lds + t * 2048;               // static A sub-buffer
    const __bf16* Bs = lds + 16384 + buf * 8192;
#pragma unroll
    for (int kk = 0; kk < 2; ++kk) {
      int b = kk * 4 + lq;
      bf16x8 a[2], bb[2];
#pragma unroll
      for (int i = 0; i < 2; ++i) {
        int row = i * 16 + lr;
        a[i] = *(const bf16x8*)(As + row * 64 + ((b ^ (row & 7)) * 8));
      }
#pragma unroll
      for (int j = 0; j < 2; ++j) {
        int row = wn + j * 16 + lr;
        bb[j] = *(const bf16x8*)(Bs + row * 64 + ((b ^ (row & 7)) * 8));
      }
#pragma unroll
      for (int i = 0; i < 2; ++i)
#pragma unroll
        for (int j = 0; j < 2; ++j)
          acc[i][j] = __builtin_amdgcn_mfma_f32_16x16x32_bf16(a[i], bb[j], acc[i][j], 0, 0, 0);
    }
    asm volatile("s_waitcnt vmcnt(0)" ::: "memory");
    __builtin_amdgcn_sched_barrier(0);
    __builtin_amdgcn_s_barrier();
    __builtin_amdgcn_sched_barrier(0);
    buf ^= 1;
  }
  int cb = bn * 128 + wn;
  int rb0 = bm * 32 + lq * 4;
#pragma unroll
  for (int j = 0; j < 2; ++j) {
    int c = cb + j * 16 + lr;
    float bv = bias[c];
#pragma unroll
    for (int i = 0; i < 2; ++i) {
      int rb = rb0 + i * 16;
#pragma unroll
      for (int rg = 0; rg < 4; ++rg) {
        size_t idx = (size_t)(rb + rg) * 512 + c;
        out[idx] = acc[i][j][rg] + bv + x[idx];
      }
    }
  }
}

extern "C" void kernel_launch(void* const* d_in, const int* in_sizes, int n_in,
                              void* d_out, int out_size, void* d_ws, size_t ws_size,
                              hipStream_t stream) {
  const float* x = (const float*)d_in[0];
  // d_in[1] = attention_mask (deterministic causal tril) -- applied analytically
  const float* uvqk = (const float*)d_in[2];
  const float* ow = (const float*)d_in[3];
  const float* obias = (const float*)d_in[4];
  float* out = (float*)d_out;

  char* w = (char*)d_ws;
  const size_t MB8 = 8u * 1024 * 1024;
  __bf16* nx    = (__bf16*)(w);             // 8 MB
  __bf16* u     = (__bf16*)(w + MB8);       // 8 MB
  __bf16* qn    = (__bf16*)(w + 2 * MB8);   // 8 MB
  __bf16* kn    = (__bf16*)(w + 3 * MB8);   // 8 MB
  __bf16* vt    = (__bf16*)(w + 4 * MB8);   // 8 MB (b, c, n) pre-scaled 1/2048
  __bf16* uvqkT = (__bf16*)(w + 5 * MB8);   // 2 MB
  __bf16* owb   = (__bf16*)(w + 5 * MB8 + 2097152);  // 0.5 MB
  size_t tail = 5 * MB8 + 2097152 + 524288;          // 42.5 MB
  __bf16* Oa    = nx;              // nx dead after k_proj

  k_prep<<<5376, 256, 0, stream>>>(x, nx, ow, owb, uvqk, uvqkT);
  k_proj<<<dim3(16, 64), 256, 0, stream>>>(nx, uvqkT, u, qn, kn, vt);

  if (ws_size >= tail + 2 * MB8) {
    // Path A: partials in ws tail; k_oinput fused into k_out.
    __bf16* Ob = (__bf16*)(w + tail);
    __bf16* Oc = (__bf16*)(w + tail + MB8);
    k_attn<<<dim3(32, 8, 3), 256, 0, stream>>>(qn, kn, vt, Oa, Ob, Oc);
    k_out_fused<<<dim3(4, 256), 256, 0, stream>>>(Oa, Ob, Oc, u, owb, obias, x, out);
  } else {
    // Path B (fallback, r8-identical): partials in d_out; separate k_oinput.
    __bf16* Ob = (__bf16*)d_out;
    __bf16* Oc = (__bf16*)d_out + (size_t)8192 * 512;
    __bf16* o_in = qn;             // qn dead after k_attn
    k_attn<<<dim3(32, 8, 3), 256, 0, stream>>>(qn, kn, vt, Oa, Ob, Oc);
    k_oinput<<<8192, 128, 0, stream>>>(Oa, Ob, Oc, u, o_in);
    k_out<<<dim3(4, 128), 256, 0, stream>>>(o_in, owb, obias, x, out);
  }
}

// Round 10
// 205.566 us; speedup vs baseline: 1.0233x; 1.0233x over previous
//
#include <hip/hip_runtime.h>

typedef __bf16 bf16x8 __attribute__((ext_vector_type(8)));
typedef float f32x4 __attribute__((ext_vector_type(4)));
typedef float f32x16 __attribute__((ext_vector_type(16)));
typedef int i32x2 __attribute__((ext_vector_type(2)));

__device__ __forceinline__ unsigned short f2bf(float f) {
  return __builtin_bit_cast(unsigned short, (__bf16)f);
}
__device__ __forceinline__ float bfu2f(unsigned short b) {
  unsigned int u = ((unsigned int)b) << 16;
  return __builtin_bit_cast(float, u);
}
// fast silu: x * rcp(1+exp(-x)).
__device__ __forceinline__ float silu_f(float x) {
  return x * __builtin_amdgcn_rcpf(1.0f + __expf(-x));
}
__device__ __forceinline__ unsigned pk2(float a, float b) {
  return (unsigned)f2bf(a) | ((unsigned)f2bf(b) << 16);
}

// Stage a tile into LDS via global_load_lds (16B/lane). Logical layout:
// [rows][CPR*8 cols] bf16. Chunk slot s of row r holds SOURCE col block
// s^(r&SWZ); readers fetch block b at slot b^(r&SWZ).
template<int CPR, int NI, int SWZ>
__device__ __forceinline__ void stage16(const __bf16* __restrict__ g, int ld,
                                        __bf16* lds, int wave, int lane) {
#pragma unroll
  for (int t = 0; t < NI; ++t) {
    int cb = (wave * NI + t) * 64;
    int c = cb + lane;
    int row = c / CPR;
    int colb = (c % CPR) ^ (row & SWZ);
    __builtin_amdgcn_global_load_lds(
        (const __attribute__((address_space(1))) unsigned int*)(g + row * ld + colb * 8),
        (__attribute__((address_space(3))) unsigned int*)(lds + cb * 8),
        16, 0, 0);
  }
}

// ---------------- fused prep kernel ----------------
__global__ void k_prep(const float* __restrict__ x, __bf16* __restrict__ nx,
                       const float* __restrict__ ow, __bf16* __restrict__ owb,
                       const float* __restrict__ uvqk, __bf16* __restrict__ uvqkT) {
  int bid = blockIdx.x, tid = threadIdx.x;
  if (bid < 4096) {
    int t = tid & 127;             // position within row
    int r = bid * 2 + (tid >> 7);  // row
    int wave = tid >> 6;           // 0..3 (2 waves per row)
    float4 v = ((const float4*)(x + (size_t)r * 512))[t];
    float s = v.x + v.y + v.z + v.w;
    float ss = v.x * v.x + v.y * v.y + v.z * v.z + v.w * v.w;
#pragma unroll
    for (int o = 32; o > 0; o >>= 1) { s += __shfl_down(s, o); ss += __shfl_down(ss, o); }
    __shared__ float red[4][2];
    if ((tid & 63) == 0) { red[wave][0] = s; red[wave][1] = ss; }
    __syncthreads();
    int rw = (wave >> 1) * 2;
    s = red[rw][0] + red[rw + 1][0];
    ss = red[rw][1] + red[rw + 1][1];
    float mu = s * (1.0f / 512.0f);
    float var = ss * (1.0f / 512.0f) - mu * mu;
    float rs = rsqrtf(var + 1e-6f);
    ushort4 o4;
    o4.x = f2bf((v.x - mu) * rs); o4.y = f2bf((v.y - mu) * rs);
    o4.z = f2bf((v.z - mu) * rs); o4.w = f2bf((v.w - mu) * rs);
    ((ushort4*)(nx + (size_t)r * 512))[t] = o4;
  } else if (bid < 4352) {
    int i = (bid - 4096) * 256 + tid;
    float4 v = ((const float4*)ow)[i];
    ushort4 o4;
    o4.x = f2bf(v.x); o4.y = f2bf(v.y); o4.z = f2bf(v.z); o4.w = f2bf(v.w);
    ((ushort4*)owb)[i] = o4;
  } else {
    __shared__ float tile[32][33];
    int bb = bid - 4352;
    int n0 = (bb & 63) * 32, k0 = (bb >> 6) * 32;
    int tx = tid & 31, ty = tid >> 5;  // 32 x 8
    for (int i = ty; i < 32; i += 8)
      tile[i][tx] = uvqk[(k0 + i) * 2048 + n0 + tx];
    __syncthreads();
    for (int i = ty; i < 32; i += 8)
      uvqkT[(n0 + i) * 512 + k0 + tx] = (__bf16)tile[tx][i];
  }
}

// ---------------- projection GEMM (v11, frozen) ----------------
__global__ __launch_bounds__(256, 2) void k_proj(
    const __bf16* __restrict__ A, const __bf16* __restrict__ Bt,
    __bf16* __restrict__ u, __bf16* __restrict__ qn,
    __bf16* __restrict__ kn, __bf16* __restrict__ vt) {
  __shared__ __bf16 lds[32768];  // 64 KB: A0@0, B0@8192, A1@16384, B1@24576
  int tid = threadIdx.x, wave = tid >> 6, lane = tid & 63;
  int lr = lane & 15, lq = lane >> 4;
  int bn = blockIdx.x, bm = blockIdx.y;
  const __bf16* Ag = A + (size_t)bm * 128 * 512;
  const __bf16* Bg = Bt + (size_t)bn * 128 * 512;
  int wm = (wave >> 1) * 64, wn = (wave & 1) * 64;
  f32x4 acc[4][4] = {};
  stage16<8, 4, 7>(Ag, 512, lds, wave, lane);
  stage16<8, 4, 7>(Bg, 512, lds + 8192, wave, lane);
  asm volatile("s_waitcnt vmcnt(0)" ::: "memory");
  __builtin_amdgcn_sched_barrier(0);
  __builtin_amdgcn_s_barrier();
  __builtin_amdgcn_sched_barrier(0);
  int buf = 0;
  for (int t = 0; t < 8; ++t) {
    if (t + 1 < 8) {
      int nb = buf ^ 1;
      stage16<8, 4, 7>(Ag + (t + 1) * 64, 512, lds + nb * 16384, wave, lane);
      stage16<8, 4, 7>(Bg + (t + 1) * 64, 512, lds + nb * 16384 + 8192, wave, lane);
    }
    const __bf16* As = lds + buf * 16384;
    const __bf16* Bs = lds + buf * 16384 + 8192;
#pragma unroll
    for (int kk = 0; kk < 2; ++kk) {
      int b = kk * 4 + lq;
      bf16x8 a[4], bb[4];
#pragma unroll
      for (int i = 0; i < 4; ++i) {
        int row = wm + i * 16 + lr;
        a[i] = *(const bf16x8*)(As + row * 64 + ((b ^ (row & 7)) * 8));
      }
#pragma unroll
      for (int j = 0; j < 4; ++j) {
        int row = wn + j * 16 + lr;
        bb[j] = *(const bf16x8*)(Bs + row * 64 + ((b ^ (row & 7)) * 8));
      }
#pragma unroll
      for (int i = 0; i < 4; ++i)
#pragma unroll
        for (int j = 0; j < 4; ++j)
          acc[i][j] = __builtin_amdgcn_mfma_f32_16x16x32_bf16(a[i], bb[j], acc[i][j], 0, 0, 0);
    }
    asm volatile("s_waitcnt vmcnt(0)" ::: "memory");
    __builtin_amdgcn_sched_barrier(0);
    __builtin_amdgcn_s_barrier();
    __builtin_amdgcn_sched_barrier(0);
    buf ^= 1;
  }
  int seg = bn >> 2;  // 128-wide block lies entirely in one 512-col segment
  int cb = (bn & 3) * 128 + wn;
  int rb0 = bm * 128 + wm + lq * 4;
  if (seg == 1) {
#pragma unroll
    for (int i = 0; i < 4; ++i) {
      int rb = rb0 + i * 16;
      int b = rb >> 11, n = rb & 2047;
#pragma unroll
      for (int j = 0; j < 4; ++j) {
        int c = cb + j * 16 + lr;
        ushort4 w;
        w.x = f2bf(silu_f(acc[i][j][0]) * (1.0f / 2048.0f));
        w.y = f2bf(silu_f(acc[i][j][1]) * (1.0f / 2048.0f));
        w.z = f2bf(silu_f(acc[i][j][2]) * (1.0f / 2048.0f));
        w.w = f2bf(silu_f(acc[i][j][3]) * (1.0f / 2048.0f));
        *(ushort4*)(vt + ((size_t)(b * 512 + c)) * 2048 + n) = w;
      }
    }
  } else {
    __bf16* dst = (seg == 0) ? u : ((seg == 2) ? qn : kn);
#pragma unroll
    for (int i = 0; i < 4; ++i) {
      int rb = rb0 + i * 16;
#pragma unroll
      for (int j = 0; j < 4; ++j) {
        int c = cb + j * 16 + lr;
#pragma unroll
        for (int rg = 0; rg < 4; ++rg)
          dst[(size_t)(rb + rg) * 512 + c] = (__bf16)silu_f(acc[i][j][rg]);
      }
    }
  }
}

// ---------------- fused causal silu-attention (v10, frozen) ----------------
template<bool DT>
__device__ __forceinline__ void attn_finish(
    const f32x16& s, int m0, int n0, int l31, int lh, int ms, bool natural,
    const __bf16* Vc, f32x16 po[2]) {
  unsigned pk[8];
#pragma unroll
  for (int q = 0; q < 8; ++q) {
    float p01[2];
#pragma unroll
    for (int h = 0; h < 2; ++h) {
      int r = 2 * q + h;
      float xx = s[r];
      float pv = xx * __builtin_amdgcn_rcpf(1.0f + __expf(-xx));
      if (DT) {
        int mrow = m0 + 4 * lh + (r & 3) + 8 * (r >> 2);
        if (mrow > n0 + l31) pv = 0.0f;
      }
      p01[h] = pv;
    }
    pk[q] = pk2(p01[0], p01[1]);
  }
  i32x2 r0 = __builtin_amdgcn_permlane32_swap((int)pk[0], (int)pk[2], false, false);
  i32x2 r1 = __builtin_amdgcn_permlane32_swap((int)pk[1], (int)pk[3], false, false);
  i32x2 r2 = __builtin_amdgcn_permlane32_swap((int)pk[4], (int)pk[6], false, false);
  i32x2 r3 = __builtin_amdgcn_permlane32_swap((int)pk[5], (int)pk[7], false, false);
  union { bf16x8 v; unsigned u[4]; } f0, f1;
  if (natural) {
    f0.u[0] = r0.x; f0.u[2] = r0.y; f0.u[1] = r1.x; f0.u[3] = r1.y;
    f1.u[0] = r2.x; f1.u[2] = r2.y; f1.u[1] = r3.x; f1.u[3] = r3.y;
  } else {
    f0.u[0] = r0.y; f0.u[2] = r0.x; f0.u[1] = r1.y; f0.u[3] = r1.x;
    f1.u[0] = r2.y; f1.u[2] = r2.x; f1.u[1] = r3.y; f1.u[3] = r3.x;
  }
  bf16x8 pf[2] = { f0.v, f1.v };
#pragma unroll
  for (int t2 = 0; t2 < 2; ++t2) {
#pragma unroll
    for (int idl = 0; idl < 2; ++idl) {
      int row = idl * 32 + l31;
      bf16x8 av = *(const bf16x8*)(Vc + row * 64 +
          (((ms * 4 + t2 * 2 + lh) ^ (row & 7)) * 8));
      po[idl] = __builtin_amdgcn_mfma_f32_32x32x16_bf16(av, pf[t2], po[idl], 0, 0, 0);
    }
  }
}

__global__ __launch_bounds__(256, 4) void k_attn(
    const __bf16* __restrict__ qn, const __bf16* __restrict__ kn,
    const __bf16* __restrict__ vt, __bf16* __restrict__ oa,
    __bf16* __restrict__ ob, __bf16* __restrict__ oc) {
  __shared__ __bf16 lds[16384];  // 32 KB
  __bf16* Kb0 = lds;             // [64 m][64 k] 8KB
  __bf16* Kb1 = lds + 4096;
  __bf16* Vb0 = lds + 8192;      // [64 dl][64 m] 8KB
  __bf16* Vb1 = lds + 12288;
  __bf16* bo = lds;              // [128 n][64 dl] 16KB over K bufs (dead at epilogue)

  int bh = blockIdx.x, p = blockIdx.y, z = blockIdx.z;
  int b = bh >> 3, hd = bh & 7;
  int tid = threadIdx.x, wave = tid >> 6, lane = tid & 63;
  int l31 = lane & 31, lh = lane >> 5;
  const __bf16* Kg = kn + (size_t)(b * 2048) * 512 + hd * 64;
  const __bf16* Vg = vt + (size_t)(b * 512 + hd * 64) * 2048;
  __bf16* Oz = (z == 0) ? oa : ((z == 1) ? ob : oc);

  i32x2 pr = __builtin_amdgcn_permlane32_swap(lh ? 10 : 11, lh ? 20 : 21, false, false);
  bool natural = (__builtin_amdgcn_readfirstlane(pr.x) == 11);

  for (int ph = 0; ph < 2; ++ph) {
    int t = ph ? (15 - p) : p;
    int T = 2 * t + 2;             // m-tiles needed for this q-tile
    int mlo = z * T / 3;
    int cnt = (z + 1) * T / 3 - mlo;
    int n0 = t * 128 + wave * 32;  // this wave's first q-row (global)
    if (ph) __syncthreads();       // epilogue LDS reads done before restaging
    const __bf16* Qg = qn + (size_t)(b * 2048 + n0 + l31) * 512 + hd * 64 + lh * 8;
    bf16x8 qf[4];
#pragma unroll
    for (int ks = 0; ks < 4; ++ks) qf[ks] = *(const bf16x8*)(Qg + ks * 16);
    if (cnt > 0) {
      stage16<8, 2, 7>(Kg + (size_t)mlo * 64 * 512, 512, Kb0, wave, lane);
      stage16<8, 2, 7>(Vg + mlo * 64, 2048, Vb0, wave, lane);
    }
    __syncthreads();

    f32x16 po[2] = {};

    for (int i = 0; i < cnt; ++i) {
      int mt = mlo + i;
      const __bf16* Kc = (i & 1) ? Kb1 : Kb0;
      const __bf16* Vc = (i & 1) ? Vb1 : Vb0;
      if (i + 1 < cnt) {
        __bf16* Kn_ = (i & 1) ? Kb0 : Kb1;
        __bf16* Vn_ = (i & 1) ? Vb0 : Vb1;
        stage16<8, 2, 7>(Kg + (size_t)(mt + 1) * 64 * 512, 512, Kn_, wave, lane);
        stage16<8, 2, 7>(Vg + (mt + 1) * 64, 2048, Vn_, wave, lane);
      }
#pragma unroll
      for (int ms = 0; ms < 2; ++ms) {
        int m0 = mt * 64 + ms * 32;       // global first m-row of subtile
        if (m0 > n0) continue;            // fully masked (32-aligned: m0<=n0 iff active)
        f32x16 s = {};
#pragma unroll
        for (int ks = 0; ks < 4; ++ks) {
          int row = ms * 32 + l31;
          bf16x8 ak = *(const bf16x8*)(Kc + row * 64 + (((ks * 2 + lh) ^ (row & 7)) * 8));
          s = __builtin_amdgcn_mfma_f32_32x32x16_bf16(ak, qf[ks], s, 0, 0, 0);
        }
        if (m0 == n0) attn_finish<true>(s, m0, n0, l31, lh, ms, natural, Vc, po);
        else          attn_finish<false>(s, m0, n0, l31, lh, ms, natural, Vc, po);
      }
      __syncthreads();
    }

    // epilogue: pack own accumulators -> xor-swizzled bounce [128 n][64 dl]
    {
      int nrow = wave * 32 + l31;
#pragma unroll
      for (int idl = 0; idl < 2; ++idl) {
#pragma unroll
        for (int g = 0; g < 4; ++g) {
          int dl0 = idl * 32 + g * 8 + lh * 4;
          int addr = nrow * 64 + ((((dl0 >> 3) ^ (nrow & 7)) << 3) | (dl0 & 7));
          ushort4 w;
          w.x = f2bf(po[idl][4 * g + 0]); w.y = f2bf(po[idl][4 * g + 1]);
          w.z = f2bf(po[idl][4 * g + 2]); w.w = f2bf(po[idl][4 * g + 3]);
          *(ushort4*)(bo + addr) = w;
        }
      }
    }
    __syncthreads();
    // coalesced store: Oz[b, t*128+n, hd*64 + c], 64B/thread
    {
      int n = tid >> 1, cc = (tid & 1) * 32;
      __bf16* gdst = Oz + (size_t)(b * 2048 + t * 128 + n) * 512 + hd * 64 + cc;
#pragma unroll
      for (int kk2 = 0; kk2 < 4; ++kk2) {
        int dlb = cc + kk2 * 8;
        int a = n * 64 + (((dlb >> 3) ^ (n & 7)) << 3);
        *(uint4*)(gdst + kk2 * 8) = *(const uint4*)(bo + a);
      }
    }
  }
}

// o_input = u * layer_norm(oa + ob + oc), one block (128 thr) per row (Path B)
__global__ void k_oinput(const __bf16* __restrict__ oa, const __bf16* __restrict__ ob,
                         const __bf16* __restrict__ oc, const __bf16* __restrict__ u,
                         __bf16* __restrict__ oin) {
  int r = blockIdx.x, t = threadIdx.x;
  ushort4 a4 = ((const ushort4*)(oa + (size_t)r * 512))[t];
  ushort4 b4 = ((const ushort4*)(ob + (size_t)r * 512))[t];
  ushort4 c4 = ((const ushort4*)(oc + (size_t)r * 512))[t];
  float a0 = bfu2f(a4.x) + bfu2f(b4.x) + bfu2f(c4.x);
  float a1 = bfu2f(a4.y) + bfu2f(b4.y) + bfu2f(c4.y);
  float a2 = bfu2f(a4.z) + bfu2f(b4.z) + bfu2f(c4.z);
  float a3 = bfu2f(a4.w) + bfu2f(b4.w) + bfu2f(c4.w);
  float s = a0 + a1 + a2 + a3;
  float ss = a0 * a0 + a1 * a1 + a2 * a2 + a3 * a3;
#pragma unroll
  for (int o = 32; o > 0; o >>= 1) { s += __shfl_down(s, o); ss += __shfl_down(ss, o); }
  __shared__ float red[4];
  if ((t & 63) == 0) { red[(t >> 6) * 2] = s; red[(t >> 6) * 2 + 1] = ss; }
  __syncthreads();
  s = red[0] + red[2]; ss = red[1] + red[3];
  float mu = s * (1.0f / 512.0f);
  float var = ss * (1.0f / 512.0f) - mu * mu;
  float rs = rsqrtf(var + 1e-6f);
  ushort4 u4 = ((const ushort4*)(u + (size_t)r * 512))[t];
  ushort4 o4;
  o4.x = f2bf(bfu2f(u4.x) * (a0 - mu) * rs);
  o4.y = f2bf(bfu2f(u4.y) * (a1 - mu) * rs);
  o4.z = f2bf(bfu2f(u4.z) * (a2 - mu) * rs);
  o4.w = f2bf(bfu2f(u4.w) * (a3 - mu) * rs);
  ((ushort4*)(oin + (size_t)r * 512))[t] = o4;
}

// Path B k_out (v11): out = o_in @ ow^T + bias + x. 64x128 tile, 2-phase dbuf.
__global__ __launch_bounds__(256, 3) void k_out(
    const __bf16* __restrict__ A, const __bf16* __restrict__ Bt,
    const float* __restrict__ bias, const float* __restrict__ x,
    float* __restrict__ out) {
  __shared__ __bf16 lds[24576];  // 48 KB: A0@0, B0@4096, A1@12288, B1@16384
  int tid = threadIdx.x, wave = tid >> 6, lane = tid & 63;
  int lr = lane & 15, lq = lane >> 4;
  int bn = blockIdx.x, bm = blockIdx.y;
  const __bf16* Ag = A + (size_t)bm * 64 * 512;
  const __bf16* Bg = Bt + (size_t)bn * 128 * 512;
  int wm = (wave >> 1) * 32, wn = (wave & 1) * 64;
  f32x4 acc[2][4] = {};
  stage16<8, 2, 7>(Ag, 512, lds, wave, lane);
  stage16<8, 4, 7>(Bg, 512, lds + 4096, wave, lane);
  asm volatile("s_waitcnt vmcnt(0)" ::: "memory");
  __builtin_amdgcn_sched_barrier(0);
  __builtin_amdgcn_s_barrier();
  __builtin_amdgcn_sched_barrier(0);
  int buf = 0;
  for (int t = 0; t < 8; ++t) {
    if (t + 1 < 8) {
      int nb = buf ^ 1;
      stage16<8, 2, 7>(Ag + (t + 1) * 64, 512, lds + nb * 12288, wave, lane);
      stage16<8, 4, 7>(Bg + (t + 1) * 64, 512, lds + nb * 12288 + 4096, wave, lane);
    }
    const __bf16* As = lds + buf * 12288;
    const __bf16* Bs = lds + buf * 12288 + 4096;
#pragma unroll
    for (int kk = 0; kk < 2; ++kk) {
      int b = kk * 4 + lq;
      bf16x8 a[2], bb[4];
#pragma unroll
      for (int i = 0; i < 2; ++i) {
        int row = wm + i * 16 + lr;
        a[i] = *(const bf16x8*)(As + row * 64 + ((b ^ (row & 7)) * 8));
      }
#pragma unroll
      for (int j = 0; j < 4; ++j) {
        int row = wn + j * 16 + lr;
        bb[j] = *(const bf16x8*)(Bs + row * 64 + ((b ^ (row & 7)) * 8));
      }
#pragma unroll
      for (int i = 0; i < 2; ++i)
#pragma unroll
        for (int j = 0; j < 4; ++j)
          acc[i][j] = __builtin_amdgcn_mfma_f32_16x16x32_bf16(a[i], bb[j], acc[i][j], 0, 0, 0);
    }
    asm volatile("s_waitcnt vmcnt(0)" ::: "memory");
    __builtin_amdgcn_sched_barrier(0);
    __builtin_amdgcn_s_barrier();
    __builtin_amdgcn_sched_barrier(0);
    buf ^= 1;
  }
  int cb = bn * 128 + wn;
  int rb0 = bm * 64 + wm + lq * 4;
#pragma unroll
  for (int j = 0; j < 4; ++j) {
    int c = cb + j * 16 + lr;
    float bv = bias[c];
#pragma unroll
    for (int i = 0; i < 2; ++i) {
      int rb = rb0 + i * 16;
#pragma unroll
      for (int rg = 0; rg < 4; ++rg) {
        size_t idx = (size_t)(rb + rg) * 512 + c;
        out[idx] = acc[i][j][rg] + bv + x[idx];
      }
    }
  }
}

// Path A v13: out = (u*LN(oa+ob+oc)) @ ow^T + bias + x.
// Grid (256) -- ONE block per 32-row group (A-prologue computed exactly once).
// 512 thr / 8 waves; wave w owns n-cols [w*64, w*64+64). A in LDS (32 KB,
// 8 swizzled sub-buffers [32][64]); B read DIRECTLY from owb (512 KB,
// L2-resident, per-lane 16B contiguous). No barriers in the K-loop.
__global__ __launch_bounds__(512, 1) void k_out_fused(
    const __bf16* __restrict__ oa, const __bf16* __restrict__ ob,
    const __bf16* __restrict__ oc, const __bf16* __restrict__ u,
    const __bf16* __restrict__ Bt, const float* __restrict__ bias,
    const float* __restrict__ x, float* __restrict__ out) {
  __shared__ __bf16 lds[16384];  // 32 KB: 8 sub-buffers [32 rows][64 cols]
  int tid = threadIdx.x, wave = tid >> 6, lane = tid & 63;
  int lr = lane & 15, lq = lane >> 4;
  int bm = blockIdx.x;

  // ---- prologue: A = u * LN(oa+ob+oc) for rows [bm*32, bm*32+32) ----
  {
    int r = tid >> 4, q = tid & 15;      // 32 rows x 16 threads/row (32 cols each)
    size_t R = (size_t)(bm * 32 + r) * 512;
    float s = 0.f, ss = 0.f;
#pragma unroll
    for (int j = 0; j < 4; ++j) {
      int c = q * 32 + j * 8;
      uint4 a4 = *(const uint4*)(oa + R + c);
      uint4 b4 = *(const uint4*)(ob + R + c);
      uint4 c4 = *(const uint4*)(oc + R + c);
#pragma unroll
      for (int e = 0; e < 4; ++e) {
        unsigned aw = ((const unsigned*)&a4)[e], bw = ((const unsigned*)&b4)[e],
                 cw = ((const unsigned*)&c4)[e];
        float v0 = bfu2f((unsigned short)aw) + bfu2f((unsigned short)bw) + bfu2f((unsigned short)cw);
        float v1 = bfu2f((unsigned short)(aw >> 16)) + bfu2f((unsigned short)(bw >> 16)) + bfu2f((unsigned short)(cw >> 16));
        s += v0 + v1; ss += v0 * v0 + v1 * v1;
      }
    }
    s += __shfl_xor(s, 1); ss += __shfl_xor(ss, 1);
    s += __shfl_xor(s, 2); ss += __shfl_xor(ss, 2);
    s += __shfl_xor(s, 4); ss += __shfl_xor(ss, 4);
    s += __shfl_xor(s, 8); ss += __shfl_xor(ss, 8);
    float mu = s * (1.0f / 512.0f);
    float var = ss * (1.0f / 512.0f) - mu * mu;
    float rs = rsqrtf(var + 1e-6f);
#pragma unroll
    for (int j = 0; j < 4; ++j) {
      int c = q * 32 + j * 8;
      uint4 a4 = *(const uint4*)(oa + R + c);
      uint4 b4 = *(const uint4*)(ob + R + c);
      uint4 c4 = *(const uint4*)(oc + R + c);
      uint4 u4 = *(const uint4*)(u + R + c);
      uint4 w;
#pragma unroll
      for (int e = 0; e < 4; ++e) {
        unsigned aw = ((const unsigned*)&a4)[e], bw = ((const unsigned*)&b4)[e],
                 cw = ((const unsigned*)&c4)[e], uw = ((const unsigned*)&u4)[e];
        float v0 = bfu2f((unsigned short)aw) + bfu2f((unsigned short)bw) + bfu2f((unsigned short)cw);
        float v1 = bfu2f((unsigned short)(aw >> 16)) + bfu2f((unsigned short)(bw >> 16)) + bfu2f((unsigned short)(cw >> 16));
        float g0 = bfu2f((unsigned short)uw) * (v0 - mu) * rs;
        float g1 = bfu2f((unsigned short)(uw >> 16)) * (v1 - mu) * rs;
        ((unsigned*)&w)[e] = pk2(g0, g1);
      }
      int j2 = c >> 6, q2 = (c & 63) >> 3;  // sub-buffer, col-block
      *(uint4*)(lds + j2 * 2048 + r * 64 + ((q2 ^ (r & 7)) * 8)) = w;
    }
  }
  __syncthreads();  // A complete; read-only below -> no more barriers

  int wn = wave * 64;
  f32x4 acc[2][4] = {};
  for (int t = 0; t < 8; ++t) {
    const __bf16* As = lds + t * 2048;
    const __bf16* Bk = Bt + t * 64;     // owb rows, k-slice t
#pragma unroll
    for (int kk = 0; kk < 2; ++kk) {
      int b = kk * 4 + lq;
      bf16x8 a[2], bb[4];
#pragma unroll
      for (int i = 0; i < 2; ++i) {
        int row = i * 16 + lr;
        a[i] = *(const bf16x8*)(As + row * 64 + ((b ^ (row & 7)) * 8));
      }
#pragma unroll
      for (int j = 0; j < 4; ++j) {
        int row = wn + j * 16 + lr;      // owb row (n), direct from global/L2
        bb[j] = *(const bf16x8*)(Bk + (size_t)row * 512 + b * 8);
      }
#pragma unroll
      for (int i = 0; i < 2; ++i)
#pragma unroll
        for (int j = 0; j < 4; ++j)
          acc[i][j] = __builtin_amdgcn_mfma_f32_16x16x32_bf16(a[i], bb[j], acc[i][j], 0, 0, 0);
    }
  }
  int rb0 = bm * 32 + lq * 4;
#pragma unroll
  for (int j = 0; j < 4; ++j) {
    int c = wn + j * 16 + lr;
    float bv = bias[c];
#pragma unroll
    for (int i = 0; i < 2; ++i) {
      int rb = rb0 + i * 16;
#pragma unroll
      for (int rg = 0; rg < 4; ++rg) {
        size_t idx = (size_t)(rb + rg) * 512 + c;
        out[idx] = acc[i][j][rg] + bv + x[idx];
      }
    }
  }
}

extern "C" void kernel_launch(void* const* d_in, const int* in_sizes, int n_in,
                              void* d_out, int out_size, void* d_ws, size_t ws_size,
                              hipStream_t stream) {
  const float* x = (const float*)d_in[0];
  // d_in[1] = attention_mask (deterministic causal tril) -- applied analytically
  const float* uvqk = (const float*)d_in[2];
  const float* ow = (const float*)d_in[3];
  const float* obias = (const float*)d_in[4];
  float* out = (float*)d_out;

  char* w = (char*)d_ws;
  const size_t MB8 = 8u * 1024 * 1024;
  __bf16* nx    = (__bf16*)(w);             // 8 MB
  __bf16* u     = (__bf16*)(w + MB8);       // 8 MB
  __bf16* qn    = (__bf16*)(w + 2 * MB8);   // 8 MB
  __bf16* kn    = (__bf16*)(w + 3 * MB8);   // 8 MB
  __bf16* vt    = (__bf16*)(w + 4 * MB8);   // 8 MB (b, c, n) pre-scaled 1/2048
  __bf16* uvqkT = (__bf16*)(w + 5 * MB8);   // 2 MB
  __bf16* owb   = (__bf16*)(w + 5 * MB8 + 2097152);  // 0.5 MB
  size_t tail = 5 * MB8 + 2097152 + 524288;          // 42.5 MB
  __bf16* Oa    = nx;              // nx dead after k_proj

  k_prep<<<5376, 256, 0, stream>>>(x, nx, ow, owb, uvqk, uvqkT);
  k_proj<<<dim3(16, 64), 256, 0, stream>>>(nx, uvqkT, u, qn, kn, vt);

  if (ws_size >= tail + 2 * MB8) {
    // Path A: partials in ws tail; k_oinput fused into k_out (grid 256,
    // one block per row-group; B direct from L2).
    __bf16* Ob = (__bf16*)(w + tail);
    __bf16* Oc = (__bf16*)(w + tail + MB8);
    k_attn<<<dim3(32, 8, 3), 256, 0, stream>>>(qn, kn, vt, Oa, Ob, Oc);
    k_out_fused<<<256, 512, 0, stream>>>(Oa, Ob, Oc, u, owb, obias, x, out);
  } else {
    // Path B (fallback, r8-identical): partials in d_out; separate k_oinput.
    __bf16* Ob = (__bf16*)d_out;
    __bf16* Oc = (__bf16*)d_out + (size_t)8192 * 512;
    __bf16* o_in = qn;             // qn dead after k_attn
    k_attn<<<dim3(32, 8, 3), 256, 0, stream>>>(qn, kn, vt, Oa, Ob, Oc);
    k_oinput<<<8192, 128, 0, stream>>>(Oa, Ob, Oc, u, o_in);
    k_out<<<dim3(4, 128), 256, 0, stream>>>(o_in, owb, obias, x, out);
  }
}

// Round 11
// 199.623 us; speedup vs baseline: 1.0537x; 1.0298x over previous
//
#include <hip/hip_runtime.h>

typedef __bf16 bf16x8 __attribute__((ext_vector_type(8)));
typedef float f32x4 __attribute__((ext_vector_type(4)));
typedef float f32x16 __attribute__((ext_vector_type(16)));
typedef int i32x2 __attribute__((ext_vector_type(2)));

__device__ __forceinline__ unsigned short f2bf(float f) {
  return __builtin_bit_cast(unsigned short, (__bf16)f);
}
__device__ __forceinline__ float bfu2f(unsigned short b) {
  unsigned int u = ((unsigned int)b) << 16;
  return __builtin_bit_cast(float, u);
}
// fast silu: x * rcp(1+exp(-x)).
__device__ __forceinline__ float silu_f(float x) {
  return x * __builtin_amdgcn_rcpf(1.0f + __expf(-x));
}
__device__ __forceinline__ unsigned pk2(float a, float b) {
  return (unsigned)f2bf(a) | ((unsigned)f2bf(b) << 16);
}

// Stage a tile into LDS via global_load_lds (16B/lane). Logical layout:
// [rows][CPR*8 cols] bf16. Chunk slot s of row r holds SOURCE col block
// s^(r&SWZ); readers fetch block b at slot b^(r&SWZ).
template<int CPR, int NI, int SWZ>
__device__ __forceinline__ void stage16(const __bf16* __restrict__ g, int ld,
                                        __bf16* lds, int wave, int lane) {
#pragma unroll
  for (int t = 0; t < NI; ++t) {
    int cb = (wave * NI + t) * 64;
    int c = cb + lane;
    int row = c / CPR;
    int colb = (c % CPR) ^ (row & SWZ);
    __builtin_amdgcn_global_load_lds(
        (const __attribute__((address_space(1))) unsigned int*)(g + row * ld + colb * 8),
        (__attribute__((address_space(3))) unsigned int*)(lds + cb * 8),
        16, 0, 0);
  }
}

// ---------------- fused prep kernel ----------------
// blocks [0,4096): layer_norm(x)->bf16, 2 rows per 256-thr block
// blocks [4096,4352): o_weight fp32->bf16
// blocks [4352,5376): uvqk (512x2048 fp32) -> uvqkT (2048x512 bf16)
__global__ void k_prep(const float* __restrict__ x, __bf16* __restrict__ nx,
                       const float* __restrict__ ow, __bf16* __restrict__ owb,
                       const float* __restrict__ uvqk, __bf16* __restrict__ uvqkT) {
  int bid = blockIdx.x, tid = threadIdx.x;
  if (bid < 4096) {
    int t = tid & 127;             // position within row
    int r = bid * 2 + (tid >> 7);  // row
    int wave = tid >> 6;           // 0..3 (2 waves per row)
    float4 v = ((const float4*)(x + (size_t)r * 512))[t];
    float s = v.x + v.y + v.z + v.w;
    float ss = v.x * v.x + v.y * v.y + v.z * v.z + v.w * v.w;
#pragma unroll
    for (int o = 32; o > 0; o >>= 1) { s += __shfl_down(s, o); ss += __shfl_down(ss, o); }
    __shared__ float red[4][2];
    if ((tid & 63) == 0) { red[wave][0] = s; red[wave][1] = ss; }
    __syncthreads();
    int rw = (wave >> 1) * 2;
    s = red[rw][0] + red[rw + 1][0];
    ss = red[rw][1] + red[rw + 1][1];
    float mu = s * (1.0f / 512.0f);
    float var = ss * (1.0f / 512.0f) - mu * mu;
    float rs = rsqrtf(var + 1e-6f);
    ushort4 o4;
    o4.x = f2bf((v.x - mu) * rs); o4.y = f2bf((v.y - mu) * rs);
    o4.z = f2bf((v.z - mu) * rs); o4.w = f2bf((v.w - mu) * rs);
    ((ushort4*)(nx + (size_t)r * 512))[t] = o4;
  } else if (bid < 4352) {
    int i = (bid - 4096) * 256 + tid;
    float4 v = ((const float4*)ow)[i];
    ushort4 o4;
    o4.x = f2bf(v.x); o4.y = f2bf(v.y); o4.z = f2bf(v.z); o4.w = f2bf(v.w);
    ((ushort4*)owb)[i] = o4;
  } else {
    __shared__ float tile[32][33];
    int bb = bid - 4352;
    int n0 = (bb & 63) * 32, k0 = (bb >> 6) * 32;
    int tx = tid & 31, ty = tid >> 5;  // 32 x 8
    for (int i = ty; i < 32; i += 8)
      tile[i][tx] = uvqk[(k0 + i) * 2048 + n0 + tx];
    __syncthreads();
    for (int i = ty; i < 32; i += 8)
      uvqkT[(n0 + i) * 512 + k0 + tx] = (__bf16)tile[tx][i];
  }
}

// ---------------- projection GEMM: mm = silu(nx @ uvqk) ----------------
// v11: 128x128 tile, 4 waves 2x2 (wave tile 64x64, 4x4 frags), 16x16x32 MFMA.
// 2-PHASE double-buffered LDS (64 KB): issue stage(t+1) BEFORE compute(t);
// one vmcnt(0)+barrier per K-step (load latency hides under MFMA).
// grid 16x64 = 1024 blocks, 2 blocks/CU.
__global__ __launch_bounds__(256, 2) void k_proj(
    const __bf16* __restrict__ A, const __bf16* __restrict__ Bt,
    __bf16* __restrict__ u, __bf16* __restrict__ qn,
    __bf16* __restrict__ kn, __bf16* __restrict__ vt) {
  __shared__ __bf16 lds[32768];  // 64 KB: A0@0, B0@8192, A1@16384, B1@24576
  int tid = threadIdx.x, wave = tid >> 6, lane = tid & 63;
  int lr = lane & 15, lq = lane >> 4;
  int bn = blockIdx.x, bm = blockIdx.y;
  const __bf16* Ag = A + (size_t)bm * 128 * 512;
  const __bf16* Bg = Bt + (size_t)bn * 128 * 512;
  int wm = (wave >> 1) * 64, wn = (wave & 1) * 64;
  f32x4 acc[4][4] = {};
  // prologue: stage K-step 0 into buf 0
  stage16<8, 4, 7>(Ag, 512, lds, wave, lane);
  stage16<8, 4, 7>(Bg, 512, lds + 8192, wave, lane);
  asm volatile("s_waitcnt vmcnt(0)" ::: "memory");
  __builtin_amdgcn_sched_barrier(0);
  __builtin_amdgcn_s_barrier();
  __builtin_amdgcn_sched_barrier(0);
  int buf = 0;
  for (int t = 0; t < 8; ++t) {
    if (t + 1 < 8) {  // issue next tile's loads first; they fly under compute
      int nb = buf ^ 1;
      stage16<8, 4, 7>(Ag + (t + 1) * 64, 512, lds + nb * 16384, wave, lane);
      stage16<8, 4, 7>(Bg + (t + 1) * 64, 512, lds + nb * 16384 + 8192, wave, lane);
    }
    const __bf16* As = lds + buf * 16384;
    const __bf16* Bs = lds + buf * 16384 + 8192;
#pragma unroll
    for (int kk = 0; kk < 2; ++kk) {
      int b = kk * 4 + lq;
      bf16x8 a[4], bb[4];
#pragma unroll
      for (int i = 0; i < 4; ++i) {
        int row = wm + i * 16 + lr;
        a[i] = *(const bf16x8*)(As + row * 64 + ((b ^ (row & 7)) * 8));
      }
#pragma unroll
      for (int j = 0; j < 4; ++j) {
        int row = wn + j * 16 + lr;
        bb[j] = *(const bf16x8*)(Bs + row * 64 + ((b ^ (row & 7)) * 8));
      }
#pragma unroll
      for (int i = 0; i < 4; ++i)
#pragma unroll
        for (int j = 0; j < 4; ++j)
          acc[i][j] = __builtin_amdgcn_mfma_f32_16x16x32_bf16(a[i], bb[j], acc[i][j], 0, 0, 0);
    }
    asm volatile("s_waitcnt vmcnt(0)" ::: "memory");  // my stage(t+1) landed
    __builtin_amdgcn_sched_barrier(0);
    __builtin_amdgcn_s_barrier();                     // all waves done: read(t) + stage(t+1)
    __builtin_amdgcn_sched_barrier(0);
    buf ^= 1;
  }
  int seg = bn >> 2;  // 128-wide block lies entirely in one 512-col segment
  int cb = (bn & 3) * 128 + wn;
  int rb0 = bm * 128 + wm + lq * 4;
  if (seg == 1) {
#pragma unroll
    for (int i = 0; i < 4; ++i) {
      int rb = rb0 + i * 16;
      int b = rb >> 11, n = rb & 2047;
#pragma unroll
      for (int j = 0; j < 4; ++j) {
        int c = cb + j * 16 + lr;
        ushort4 w;
        w.x = f2bf(silu_f(acc[i][j][0]) * (1.0f / 2048.0f));
        w.y = f2bf(silu_f(acc[i][j][1]) * (1.0f / 2048.0f));
        w.z = f2bf(silu_f(acc[i][j][2]) * (1.0f / 2048.0f));
        w.w = f2bf(silu_f(acc[i][j][3]) * (1.0f / 2048.0f));
        *(ushort4*)(vt + ((size_t)(b * 512 + c)) * 2048 + n) = w;
      }
    }
  } else {
    __bf16* dst = (seg == 0) ? u : ((seg == 2) ? qn : kn);
#pragma unroll
    for (int i = 0; i < 4; ++i) {
      int rb = rb0 + i * 16;
#pragma unroll
      for (int j = 0; j < 4; ++j) {
        int c = cb + j * 16 + lr;
#pragma unroll
        for (int rg = 0; rg < 4; ++rg)
          dst[(size_t)(rb + rg) * 512 + c] = (__bf16)silu_f(acc[i][j][rg]);
      }
    }
  }
}

// ---------------- fused causal silu-attention (v10, frozen) ----------------
// v5 structure: Q-tile 128 rows, 4 waves each own a 32-row n-slice, K/V
// double-buffered 32KB LDS, full-drain __syncthreads per m-tile, grid
// (32,8,3)=768 blocks. Diagonal mask compile-time templated; exchange via
// permlane32_swap. Measured 42.5us.
template<bool DT>
__device__ __forceinline__ void attn_finish(
    const f32x16& s, int m0, int n0, int l31, int lh, int ms, bool natural,
    const __bf16* Vc, f32x16 po[2]) {
  unsigned pk[8];
#pragma unroll
  for (int q = 0; q < 8; ++q) {
    float p01[2];
#pragma unroll
    for (int h = 0; h < 2; ++h) {
      int r = 2 * q + h;
      float xx = s[r];
      float pv = xx * __builtin_amdgcn_rcpf(1.0f + __expf(-xx));
      if (DT) {
        int mrow = m0 + 4 * lh + (r & 3) + 8 * (r >> 2);
        if (mrow > n0 + l31) pv = 0.0f;
      }
      p01[h] = pv;
    }
    pk[q] = pk2(p01[0], p01[1]);
  }
  // cross-half exchange: pair (lo half's pk[q], hi half's pk[q+2]) swap
  i32x2 r0 = __builtin_amdgcn_permlane32_swap((int)pk[0], (int)pk[2], false, false);
  i32x2 r1 = __builtin_amdgcn_permlane32_swap((int)pk[1], (int)pk[3], false, false);
  i32x2 r2 = __builtin_amdgcn_permlane32_swap((int)pk[4], (int)pk[6], false, false);
  i32x2 r3 = __builtin_amdgcn_permlane32_swap((int)pk[5], (int)pk[7], false, false);
  union { bf16x8 v; unsigned u[4]; } f0, f1;
  if (natural) {
    f0.u[0] = r0.x; f0.u[2] = r0.y; f0.u[1] = r1.x; f0.u[3] = r1.y;
    f1.u[0] = r2.x; f1.u[2] = r2.y; f1.u[1] = r3.x; f1.u[3] = r3.y;
  } else {
    f0.u[0] = r0.y; f0.u[2] = r0.x; f0.u[1] = r1.y; f0.u[3] = r1.x;
    f1.u[0] = r2.y; f1.u[2] = r2.x; f1.u[1] = r3.y; f1.u[3] = r3.x;
  }
  bf16x8 pf[2] = { f0.v, f1.v };
  // out^T[dl 64][n 32] += V^T . P^T (K-range: this subtile's 32 m)
#pragma unroll
  for (int t2 = 0; t2 < 2; ++t2) {
#pragma unroll
    for (int idl = 0; idl < 2; ++idl) {
      int row = idl * 32 + l31;
      bf16x8 av = *(const bf16x8*)(Vc + row * 64 +
          (((ms * 4 + t2 * 2 + lh) ^ (row & 7)) * 8));
      po[idl] = __builtin_amdgcn_mfma_f32_32x32x16_bf16(av, pf[t2], po[idl], 0, 0, 0);
    }
  }
}

__global__ __launch_bounds__(256, 4) void k_attn(
    const __bf16* __restrict__ qn, const __bf16* __restrict__ kn,
    const __bf16* __restrict__ vt, __bf16* __restrict__ oa,
    __bf16* __restrict__ ob, __bf16* __restrict__ oc) {
  __shared__ __bf16 lds[16384];  // 32 KB
  __bf16* Kb0 = lds;             // [64 m][64 k] 8KB
  __bf16* Kb1 = lds + 4096;
  __bf16* Vb0 = lds + 8192;      // [64 dl][64 m] 8KB
  __bf16* Vb1 = lds + 12288;
  __bf16* bo = lds;              // [128 n][64 dl] 16KB over K bufs (dead at epilogue)

  int bh = blockIdx.x, p = blockIdx.y, z = blockIdx.z;
  int b = bh >> 3, hd = bh & 7;
  int tid = threadIdx.x, wave = tid >> 6, lane = tid & 63;
  int l31 = lane & 31, lh = lane >> 5;
  const __bf16* Kg = kn + (size_t)(b * 2048) * 512 + hd * 64;
  const __bf16* Vg = vt + (size_t)(b * 512 + hd * 64) * 2048;
  __bf16* Oz = (z == 0) ? oa : ((z == 1) ? ob : oc);

  // permlane32_swap operand-order probe (wave-uniform)
  i32x2 pr = __builtin_amdgcn_permlane32_swap(lh ? 10 : 11, lh ? 20 : 21, false, false);
  bool natural = (__builtin_amdgcn_readfirstlane(pr.x) == 11);

  for (int ph = 0; ph < 2; ++ph) {
    int t = ph ? (15 - p) : p;
    int T = 2 * t + 2;             // m-tiles needed for this q-tile
    int mlo = z * T / 3;
    int cnt = (z + 1) * T / 3 - mlo;
    int n0 = t * 128 + wave * 32;  // this wave's first q-row (global)
    if (ph) __syncthreads();       // epilogue LDS reads done before restaging
    // Q fragments direct from global (held in regs for the whole m-loop)
    const __bf16* Qg = qn + (size_t)(b * 2048 + n0 + l31) * 512 + hd * 64 + lh * 8;
    bf16x8 qf[4];
#pragma unroll
    for (int ks = 0; ks < 4; ++ks) qf[ks] = *(const bf16x8*)(Qg + ks * 16);
    if (cnt > 0) {
      stage16<8, 2, 7>(Kg + (size_t)mlo * 64 * 512, 512, Kb0, wave, lane);
      stage16<8, 2, 7>(Vg + mlo * 64, 2048, Vb0, wave, lane);
    }
    __syncthreads();

    f32x16 po[2] = {};

    for (int i = 0; i < cnt; ++i) {
      int mt = mlo + i;
      const __bf16* Kc = (i & 1) ? Kb1 : Kb0;
      const __bf16* Vc = (i & 1) ? Vb1 : Vb0;
      if (i + 1 < cnt) {
        __bf16* Kn_ = (i & 1) ? Kb0 : Kb1;
        __bf16* Vn_ = (i & 1) ? Vb0 : Vb1;
        stage16<8, 2, 7>(Kg + (size_t)(mt + 1) * 64 * 512, 512, Kn_, wave, lane);
        stage16<8, 2, 7>(Vg + (mt + 1) * 64, 2048, Vn_, wave, lane);
      }
#pragma unroll
      for (int ms = 0; ms < 2; ++ms) {
        int m0 = mt * 64 + ms * 32;       // global first m-row of subtile
        if (m0 > n0) continue;            // fully masked (32-aligned: m0<=n0 iff active)
        // S^T[m 32][n 32] = K . Q^T
        f32x16 s = {};
#pragma unroll
        for (int ks = 0; ks < 4; ++ks) {
          int row = ms * 32 + l31;
          bf16x8 ak = *(const bf16x8*)(Kc + row * 64 + (((ks * 2 + lh) ^ (row & 7)) * 8));
          s = __builtin_amdgcn_mfma_f32_32x32x16_bf16(ak, qf[ks], s, 0, 0, 0);
        }
        if (m0 == n0) attn_finish<true>(s, m0, n0, l31, lh, ms, natural, Vc, po);
        else          attn_finish<false>(s, m0, n0, l31, lh, ms, natural, Vc, po);
      }
      __syncthreads();
    }

    // epilogue: pack own accumulators -> xor-swizzled bounce [128 n][64 dl]
    {
      int nrow = wave * 32 + l31;
#pragma unroll
      for (int idl = 0; idl < 2; ++idl) {
#pragma unroll
        for (int g = 0; g < 4; ++g) {
          int dl0 = idl * 32 + g * 8 + lh * 4;
          int addr = nrow * 64 + ((((dl0 >> 3) ^ (nrow & 7)) << 3) | (dl0 & 7));
          ushort4 w;
          w.x = f2bf(po[idl][4 * g + 0]); w.y = f2bf(po[idl][4 * g + 1]);
          w.z = f2bf(po[idl][4 * g + 2]); w.w = f2bf(po[idl][4 * g + 3]);
          *(ushort4*)(bo + addr) = w;
        }
      }
    }
    __syncthreads();
    // coalesced store: Oz[b, t*128+n, hd*64 + c], 64B/thread
    {
      int n = tid >> 1, cc = (tid & 1) * 32;
      __bf16* gdst = Oz + (size_t)(b * 2048 + t * 128 + n) * 512 + hd * 64 + cc;
#pragma unroll
      for (int kk2 = 0; kk2 < 4; ++kk2) {
        int dlb = cc + kk2 * 8;
        int a = n * 64 + (((dlb >> 3) ^ (n & 7)) << 3);
        *(uint4*)(gdst + kk2 * 8) = *(const uint4*)(bo + a);
      }
    }
  }
}

// o_input = u * layer_norm(oa + ob + oc), one block (128 thr) per row
__global__ void k_oinput(const __bf16* __restrict__ oa, const __bf16* __restrict__ ob,
                         const __bf16* __restrict__ oc, const __bf16* __restrict__ u,
                         __bf16* __restrict__ oin) {
  int r = blockIdx.x, t = threadIdx.x;
  ushort4 a4 = ((const ushort4*)(oa + (size_t)r * 512))[t];
  ushort4 b4 = ((const ushort4*)(ob + (size_t)r * 512))[t];
  ushort4 c4 = ((const ushort4*)(oc + (size_t)r * 512))[t];
  float a0 = bfu2f(a4.x) + bfu2f(b4.x) + bfu2f(c4.x);
  float a1 = bfu2f(a4.y) + bfu2f(b4.y) + bfu2f(c4.y);
  float a2 = bfu2f(a4.z) + bfu2f(b4.z) + bfu2f(c4.z);
  float a3 = bfu2f(a4.w) + bfu2f(b4.w) + bfu2f(c4.w);
  float s = a0 + a1 + a2 + a3;
  float ss = a0 * a0 + a1 * a1 + a2 * a2 + a3 * a3;
#pragma unroll
  for (int o = 32; o > 0; o >>= 1) { s += __shfl_down(s, o); ss += __shfl_down(ss, o); }
  __shared__ float red[4];
  if ((t & 63) == 0) { red[(t >> 6) * 2] = s; red[(t >> 6) * 2 + 1] = ss; }
  __syncthreads();
  s = red[0] + red[2]; ss = red[1] + red[3];
  float mu = s * (1.0f / 512.0f);
  float var = ss * (1.0f / 512.0f) - mu * mu;
  float rs = rsqrtf(var + 1e-6f);
  ushort4 u4 = ((const ushort4*)(u + (size_t)r * 512))[t];
  ushort4 o4;
  o4.x = f2bf(bfu2f(u4.x) * (a0 - mu) * rs);
  o4.y = f2bf(bfu2f(u4.y) * (a1 - mu) * rs);
  o4.z = f2bf(bfu2f(u4.z) * (a2 - mu) * rs);
  o4.w = f2bf(bfu2f(u4.w) * (a3 - mu) * rs);
  ((ushort4*)(oin + (size_t)r * 512))[t] = o4;
}

// out = o_in @ ow^T + bias + x.  M=8192, N=512, K=512.
// v11: 64x128 tile, 2-PHASE double-buffered LDS (48 KB), one vmcnt(0)+barrier
// per K-step. grid 4x128 = 512 blocks, 3 blocks/CU.
__global__ __launch_bounds__(256, 3) void k_out(
    const __bf16* __restrict__ A, const __bf16* __restrict__ Bt,
    const float* __restrict__ bias, const float* __restrict__ x,
    float* __restrict__ out) {
  __shared__ __bf16 lds[24576];  // 48 KB: A0@0, B0@4096, A1@12288, B1@16384
  int tid = threadIdx.x, wave = tid >> 6, lane = tid & 63;
  int lr = lane & 15, lq = lane >> 4;
  int bn = blockIdx.x, bm = blockIdx.y;
  const __bf16* Ag = A + (size_t)bm * 64 * 512;
  const __bf16* Bg = Bt + (size_t)bn * 128 * 512;
  int wm = (wave >> 1) * 32, wn = (wave & 1) * 64;
  f32x4 acc[2][4] = {};
  // prologue: stage K-step 0 into buf 0
  stage16<8, 2, 7>(Ag, 512, lds, wave, lane);
  stage16<8, 4, 7>(Bg, 512, lds + 4096, wave, lane);
  asm volatile("s_waitcnt vmcnt(0)" ::: "memory");
  __builtin_amdgcn_sched_barrier(0);
  __builtin_amdgcn_s_barrier();
  __builtin_amdgcn_sched_barrier(0);
  int buf = 0;
  for (int t = 0; t < 8; ++t) {
    if (t + 1 < 8) {
      int nb = buf ^ 1;
      stage16<8, 2, 7>(Ag + (t + 1) * 64, 512, lds + nb * 12288, wave, lane);
      stage16<8, 4, 7>(Bg + (t + 1) * 64, 512, lds + nb * 12288 + 4096, wave, lane);
    }
    const __bf16* As = lds + buf * 12288;
    const __bf16* Bs = lds + buf * 12288 + 4096;
#pragma unroll
    for (int kk = 0; kk < 2; ++kk) {
      int b = kk * 4 + lq;
      bf16x8 a[2], bb[4];
#pragma unroll
      for (int i = 0; i < 2; ++i) {
        int row = wm + i * 16 + lr;
        a[i] = *(const bf16x8*)(As + row * 64 + ((b ^ (row & 7)) * 8));
      }
#pragma unroll
      for (int j = 0; j < 4; ++j) {
        int row = wn + j * 16 + lr;
        bb[j] = *(const bf16x8*)(Bs + row * 64 + ((b ^ (row & 7)) * 8));
      }
#pragma unroll
      for (int i = 0; i < 2; ++i)
#pragma unroll
        for (int j = 0; j < 4; ++j)
          acc[i][j] = __builtin_amdgcn_mfma_f32_16x16x32_bf16(a[i], bb[j], acc[i][j], 0, 0, 0);
    }
    asm volatile("s_waitcnt vmcnt(0)" ::: "memory");
    __builtin_amdgcn_sched_barrier(0);
    __builtin_amdgcn_s_barrier();
    __builtin_amdgcn_sched_barrier(0);
    buf ^= 1;
  }
  int cb = bn * 128 + wn;
  int rb0 = bm * 64 + wm + lq * 4;
#pragma unroll
  for (int j = 0; j < 4; ++j) {
    int c = cb + j * 16 + lr;
    float bv = bias[c];
#pragma unroll
    for (int i = 0; i < 2; ++i) {
      int rb = rb0 + i * 16;
#pragma unroll
      for (int rg = 0; rg < 4; ++rg) {
        size_t idx = (size_t)(rb + rg) * 512 + c;
        out[idx] = acc[i][j][rg] + bv + x[idx];
      }
    }
  }
}

extern "C" void kernel_launch(void* const* d_in, const int* in_sizes, int n_in,
                              void* d_out, int out_size, void* d_ws, size_t ws_size,
                              hipStream_t stream) {
  const float* x = (const float*)d_in[0];
  // d_in[1] = attention_mask (deterministic causal tril) -- applied analytically
  const float* uvqk = (const float*)d_in[2];
  const float* ow = (const float*)d_in[3];
  const float* obias = (const float*)d_in[4];
  float* out = (float*)d_out;

  char* w = (char*)d_ws;
  const size_t MB8 = 8u * 1024 * 1024;
  __bf16* nx    = (__bf16*)(w);             // 8 MB
  __bf16* u     = (__bf16*)(w + MB8);       // 8 MB
  __bf16* qn    = (__bf16*)(w + 2 * MB8);   // 8 MB
  __bf16* kn    = (__bf16*)(w + 3 * MB8);   // 8 MB
  __bf16* vt    = (__bf16*)(w + 4 * MB8);   // 8 MB (b, c, n) pre-scaled 1/2048
  __bf16* uvqkT = (__bf16*)(w + 5 * MB8);   // 2 MB
  __bf16* owb   = (__bf16*)(w + 5 * MB8 + 2097152);  // 0.5 MB
  __bf16* Oa    = nx;              // nx dead after k_proj
  __bf16* Ob    = (__bf16*)d_out;  // scratch in d_out (first 8 MB of 16 MB)
  __bf16* Oc    = (__bf16*)d_out + (size_t)8192 * 512;  // second 8 MB of d_out
  __bf16* o_in  = qn;              // qn dead after k_attn

  k_prep<<<5376, 256, 0, stream>>>(x, nx, ow, owb, uvqk, uvqkT);
  k_proj<<<dim3(16, 64), 256, 0, stream>>>(nx, uvqkT, u, qn, kn, vt);
  k_attn<<<dim3(32, 8, 3), 256, 0, stream>>>(qn, kn, vt, Oa, Ob, Oc);
  k_oinput<<<8192, 128, 0, stream>>>(Oa, Ob, Oc, u, o_in);
  k_out<<<dim3(4, 128), 256, 0, stream>>>(o_in, owb, obias, x, out);
}

// Round 12
// 191.009 us; speedup vs baseline: 1.1012x; 1.0451x over previous
//
#include <hip/hip_runtime.h>

typedef __bf16 bf16x8 __attribute__((ext_vector_type(8)));
typedef float f32x4 __attribute__((ext_vector_type(4)));
typedef float f32x16 __attribute__((ext_vector_type(16)));
typedef int i32x2 __attribute__((ext_vector_type(2)));

__device__ __forceinline__ unsigned short f2bf(float f) {
  return __builtin_bit_cast(unsigned short, (__bf16)f);
}
__device__ __forceinline__ float bfu2f(unsigned short b) {
  unsigned int u = ((unsigned int)b) << 16;
  return __builtin_bit_cast(float, u);
}
// fast silu: x * rcp(1+exp(-x)).
__device__ __forceinline__ float silu_f(float x) {
  return x * __builtin_amdgcn_rcpf(1.0f + __expf(-x));
}
__device__ __forceinline__ unsigned pk2(float a, float b) {
  return (unsigned)f2bf(a) | ((unsigned)f2bf(b) << 16);
}

// Stage a tile into LDS via global_load_lds (16B/lane). Logical layout:
// [rows][CPR*8 cols] bf16. Chunk slot s of row r holds SOURCE col block
// s^(r&SWZ); readers fetch block b at slot b^(r&SWZ).
template<int CPR, int NI, int SWZ>
__device__ __forceinline__ void stage16(const __bf16* __restrict__ g, int ld,
                                        __bf16* lds, int wave, int lane) {
#pragma unroll
  for (int t = 0; t < NI; ++t) {
    int cb = (wave * NI + t) * 64;
    int c = cb + lane;
    int row = c / CPR;
    int colb = (c % CPR) ^ (row & SWZ);
    __builtin_amdgcn_global_load_lds(
        (const __attribute__((address_space(1))) unsigned int*)(g + row * ld + colb * 8),
        (__attribute__((address_space(3))) unsigned int*)(lds + cb * 8),
        16, 0, 0);
  }
}

// ---------------- fused prep kernel ----------------
// blocks [0,4096): layer_norm(x)->bf16, 2 rows per 256-thr block
// blocks [4096,4352): o_weight fp32->bf16
// blocks [4352,5376): uvqk (512x2048 fp32) -> uvqkT (2048x512 bf16)
__global__ void k_prep(const float* __restrict__ x, __bf16* __restrict__ nx,
                       const float* __restrict__ ow, __bf16* __restrict__ owb,
                       const float* __restrict__ uvqk, __bf16* __restrict__ uvqkT) {
  int bid = blockIdx.x, tid = threadIdx.x;
  if (bid < 4096) {
    int t = tid & 127;             // position within row
    int r = bid * 2 + (tid >> 7);  // row
    int wave = tid >> 6;           // 0..3 (2 waves per row)
    float4 v = ((const float4*)(x + (size_t)r * 512))[t];
    float s = v.x + v.y + v.z + v.w;
    float ss = v.x * v.x + v.y * v.y + v.z * v.z + v.w * v.w;
#pragma unroll
    for (int o = 32; o > 0; o >>= 1) { s += __shfl_down(s, o); ss += __shfl_down(ss, o); }
    __shared__ float red[4][2];
    if ((tid & 63) == 0) { red[wave][0] = s; red[wave][1] = ss; }
    __syncthreads();
    int rw = (wave >> 1) * 2;
    s = red[rw][0] + red[rw + 1][0];
    ss = red[rw][1] + red[rw + 1][1];
    float mu = s * (1.0f / 512.0f);
    float var = ss * (1.0f / 512.0f) - mu * mu;
    float rs = rsqrtf(var + 1e-6f);
    ushort4 o4;
    o4.x = f2bf((v.x - mu) * rs); o4.y = f2bf((v.y - mu) * rs);
    o4.z = f2bf((v.z - mu) * rs); o4.w = f2bf((v.w - mu) * rs);
    ((ushort4*)(nx + (size_t)r * 512))[t] = o4;
  } else if (bid < 4352) {
    int i = (bid - 4096) * 256 + tid;
    float4 v = ((const float4*)ow)[i];
    ushort4 o4;
    o4.x = f2bf(v.x); o4.y = f2bf(v.y); o4.z = f2bf(v.z); o4.w = f2bf(v.w);
    ((ushort4*)owb)[i] = o4;
  } else {
    __shared__ float tile[32][33];
    int bb = bid - 4352;
    int n0 = (bb & 63) * 32, k0 = (bb >> 6) * 32;
    int tx = tid & 31, ty = tid >> 5;  // 32 x 8
    for (int i = ty; i < 32; i += 8)
      tile[i][tx] = uvqk[(k0 + i) * 2048 + n0 + tx];
    __syncthreads();
    for (int i = ty; i < 32; i += 8)
      uvqkT[(n0 + i) * 512 + k0 + tx] = (__bf16)tile[tx][i];
  }
}

// ---------------- projection GEMM: mm = silu(nx @ uvqk) ----------------
// v11: 128x128 tile, 4 waves 2x2 (wave tile 64x64, 4x4 frags), 16x16x32 MFMA.
// 2-PHASE double-buffered LDS (64 KB). grid 16x64 = 1024 blocks, 2 blocks/CU.
__global__ __launch_bounds__(256, 2) void k_proj(
    const __bf16* __restrict__ A, const __bf16* __restrict__ Bt,
    __bf16* __restrict__ u, __bf16* __restrict__ qn,
    __bf16* __restrict__ kn, __bf16* __restrict__ vt) {
  __shared__ __bf16 lds[32768];  // 64 KB: A0@0, B0@8192, A1@16384, B1@24576
  int tid = threadIdx.x, wave = tid >> 6, lane = tid & 63;
  int lr = lane & 15, lq = lane >> 4;
  int bn = blockIdx.x, bm = blockIdx.y;
  const __bf16* Ag = A + (size_t)bm * 128 * 512;
  const __bf16* Bg = Bt + (size_t)bn * 128 * 512;
  int wm = (wave >> 1) * 64, wn = (wave & 1) * 64;
  f32x4 acc[4][4] = {};
  // prologue: stage K-step 0 into buf 0
  stage16<8, 4, 7>(Ag, 512, lds, wave, lane);
  stage16<8, 4, 7>(Bg, 512, lds + 8192, wave, lane);
  asm volatile("s_waitcnt vmcnt(0)" ::: "memory");
  __builtin_amdgcn_sched_barrier(0);
  __builtin_amdgcn_s_barrier();
  __builtin_amdgcn_sched_barrier(0);
  int buf = 0;
  for (int t = 0; t < 8; ++t) {
    if (t + 1 < 8) {  // issue next tile's loads first; they fly under compute
      int nb = buf ^ 1;
      stage16<8, 4, 7>(Ag + (t + 1) * 64, 512, lds + nb * 16384, wave, lane);
      stage16<8, 4, 7>(Bg + (t + 1) * 64, 512, lds + nb * 16384 + 8192, wave, lane);
    }
    const __bf16* As = lds + buf * 16384;
    const __bf16* Bs = lds + buf * 16384 + 8192;
#pragma unroll
    for (int kk = 0; kk < 2; ++kk) {
      int b = kk * 4 + lq;
      bf16x8 a[4], bb[4];
#pragma unroll
      for (int i = 0; i < 4; ++i) {
        int row = wm + i * 16 + lr;
        a[i] = *(const bf16x8*)(As + row * 64 + ((b ^ (row & 7)) * 8));
      }
#pragma unroll
      for (int j = 0; j < 4; ++j) {
        int row = wn + j * 16 + lr;
        bb[j] = *(const bf16x8*)(Bs + row * 64 + ((b ^ (row & 7)) * 8));
      }
#pragma unroll
      for (int i = 0; i < 4; ++i)
#pragma unroll
        for (int j = 0; j < 4; ++j)
          acc[i][j] = __builtin_amdgcn_mfma_f32_16x16x32_bf16(a[i], bb[j], acc[i][j], 0, 0, 0);
    }
    asm volatile("s_waitcnt vmcnt(0)" ::: "memory");  // my stage(t+1) landed
    __builtin_amdgcn_sched_barrier(0);
    __builtin_amdgcn_s_barrier();                     // all waves done: read(t) + stage(t+1)
    __builtin_amdgcn_sched_barrier(0);
    buf ^= 1;
  }
  int seg = bn >> 2;  // 128-wide block lies entirely in one 512-col segment
  int cb = (bn & 3) * 128 + wn;
  int rb0 = bm * 128 + wm + lq * 4;
  if (seg == 1) {
#pragma unroll
    for (int i = 0; i < 4; ++i) {
      int rb = rb0 + i * 16;
      int b = rb >> 11, n = rb & 2047;
#pragma unroll
      for (int j = 0; j < 4; ++j) {
        int c = cb + j * 16 + lr;
        ushort4 w;
        w.x = f2bf(silu_f(acc[i][j][0]) * (1.0f / 2048.0f));
        w.y = f2bf(silu_f(acc[i][j][1]) * (1.0f / 2048.0f));
        w.z = f2bf(silu_f(acc[i][j][2]) * (1.0f / 2048.0f));
        w.w = f2bf(silu_f(acc[i][j][3]) * (1.0f / 2048.0f));
        *(ushort4*)(vt + ((size_t)(b * 512 + c)) * 2048 + n) = w;
      }
    }
  } else {
    __bf16* dst = (seg == 0) ? u : ((seg == 2) ? qn : kn);
#pragma unroll
    for (int i = 0; i < 4; ++i) {
      int rb = rb0 + i * 16;
#pragma unroll
      for (int j = 0; j < 4; ++j) {
        int c = cb + j * 16 + lr;
#pragma unroll
        for (int rg = 0; rg < 4; ++rg)
          dst[(size_t)(rb + rg) * 512 + c] = (__bf16)silu_f(acc[i][j][rg]);
      }
    }
  }
}

// ---------------- fused causal silu-attention (v14) ----------------
// v10 compute body; m-tile DOUBLED to 128 rows (K/V dbuf 64KB LDS): barriers,
// vmcnt drains and stage calls per unit work halve. nz=2 -> grid (32,8,2)=512
// blocks = exactly 2/CU, one clean pass, 2 partial buffers.
template<bool DT>
__device__ __forceinline__ void attn_finish(
    const f32x16& s, int m0, int n0, int l31, int lh, int ms, bool natural,
    const __bf16* Vc, f32x16 po[2]) {
  unsigned pk[8];
#pragma unroll
  for (int q = 0; q < 8; ++q) {
    float p01[2];
#pragma unroll
    for (int h = 0; h < 2; ++h) {
      int r = 2 * q + h;
      float xx = s[r];
      float pv = xx * __builtin_amdgcn_rcpf(1.0f + __expf(-xx));
      if (DT) {
        int mrow = m0 + 4 * lh + (r & 3) + 8 * (r >> 2);
        if (mrow > n0 + l31) pv = 0.0f;
      }
      p01[h] = pv;
    }
    pk[q] = pk2(p01[0], p01[1]);
  }
  // cross-half exchange: pair (lo half's pk[q], hi half's pk[q+2]) swap
  i32x2 r0 = __builtin_amdgcn_permlane32_swap((int)pk[0], (int)pk[2], false, false);
  i32x2 r1 = __builtin_amdgcn_permlane32_swap((int)pk[1], (int)pk[3], false, false);
  i32x2 r2 = __builtin_amdgcn_permlane32_swap((int)pk[4], (int)pk[6], false, false);
  i32x2 r3 = __builtin_amdgcn_permlane32_swap((int)pk[5], (int)pk[7], false, false);
  union { bf16x8 v; unsigned u[4]; } f0, f1;
  if (natural) {
    f0.u[0] = r0.x; f0.u[2] = r0.y; f0.u[1] = r1.x; f0.u[3] = r1.y;
    f1.u[0] = r2.x; f1.u[2] = r2.y; f1.u[1] = r3.x; f1.u[3] = r3.y;
  } else {
    f0.u[0] = r0.y; f0.u[2] = r0.x; f0.u[1] = r1.y; f0.u[3] = r1.x;
    f1.u[0] = r2.y; f1.u[2] = r2.x; f1.u[1] = r3.y; f1.u[3] = r3.x;
  }
  bf16x8 pf[2] = { f0.v, f1.v };
  // out^T[dl 64][n 32] += V^T . P^T; V LDS is [64 dl][128 m] (16 col-blocks)
#pragma unroll
  for (int t2 = 0; t2 < 2; ++t2) {
#pragma unroll
    for (int idl = 0; idl < 2; ++idl) {
      int row = idl * 32 + l31;
      bf16x8 av = *(const bf16x8*)(Vc + row * 128 +
          (((ms * 4 + t2 * 2 + lh) ^ (row & 7)) * 8));
      po[idl] = __builtin_amdgcn_mfma_f32_32x32x16_bf16(av, pf[t2], po[idl], 0, 0, 0);
    }
  }
}

__global__ __launch_bounds__(256, 2) void k_attn(
    const __bf16* __restrict__ qn, const __bf16* __restrict__ kn,
    const __bf16* __restrict__ vt, __bf16* __restrict__ oa,
    __bf16* __restrict__ ob) {
  __shared__ __bf16 lds[32768];  // 64 KB: K0@0, K1@8192 ([128 m][64 k] 16KB each)
                                 //        V0@16384, V1@24576 ([64 dl][128 m])
  __bf16* bo = lds;              // [128 n][64 dl] 16KB over K0 (dead at epilogue)

  int bh = blockIdx.x, p = blockIdx.y, z = blockIdx.z;
  int b = bh >> 3, hd = bh & 7;
  int tid = threadIdx.x, wave = tid >> 6, lane = tid & 63;
  int l31 = lane & 31, lh = lane >> 5;
  const __bf16* Kg = kn + (size_t)(b * 2048) * 512 + hd * 64;
  const __bf16* Vg = vt + (size_t)(b * 512 + hd * 64) * 2048;
  __bf16* Oz = z ? ob : oa;

  // permlane32_swap operand-order probe (wave-uniform)
  i32x2 pr = __builtin_amdgcn_permlane32_swap(lh ? 10 : 11, lh ? 20 : 21, false, false);
  bool natural = (__builtin_amdgcn_readfirstlane(pr.x) == 11);

  for (int ph = 0; ph < 2; ++ph) {
    int t = ph ? (15 - p) : p;
    int T = t + 1;                 // 128-row m-tiles needed for this q-tile
    int mlo = z * T / 2;
    int cnt = (z + 1) * T / 2 - mlo;
    int n0 = t * 128 + wave * 32;  // this wave's first q-row (global)
    if (ph) __syncthreads();       // epilogue LDS reads done before restaging
    // Q fragments direct from global (held in regs for the whole m-loop)
    const __bf16* Qg = qn + (size_t)(b * 2048 + n0 + l31) * 512 + hd * 64 + lh * 8;
    bf16x8 qf[4];
#pragma unroll
    for (int ks = 0; ks < 4; ++ks) qf[ks] = *(const bf16x8*)(Qg + ks * 16);
    if (cnt > 0) {
      stage16<8, 4, 7>(Kg + (size_t)mlo * 128 * 512, 512, lds, wave, lane);
      stage16<16, 4, 7>(Vg + mlo * 128, 2048, lds + 16384, wave, lane);
    }
    __syncthreads();

    f32x16 po[2] = {};

    for (int i = 0; i < cnt; ++i) {
      int mt = mlo + i;
      const __bf16* Kc = lds + (i & 1) * 8192;
      const __bf16* Vc = lds + 16384 + (i & 1) * 8192;
      if (i + 1 < cnt) {
        __bf16* Kn_ = lds + ((i & 1) ^ 1) * 8192;
        __bf16* Vn_ = lds + 16384 + ((i & 1) ^ 1) * 8192;
        stage16<8, 4, 7>(Kg + (size_t)(mt + 1) * 128 * 512, 512, Kn_, wave, lane);
        stage16<16, 4, 7>(Vg + (mt + 1) * 128, 2048, Vn_, wave, lane);
      }
#pragma unroll
      for (int ms = 0; ms < 4; ++ms) {
        int m0 = mt * 128 + ms * 32;      // global first m-row of subtile
        if (m0 > n0) continue;            // fully masked (32-aligned: m0<=n0 iff active)
        // S^T[m 32][n 32] = K . Q^T
        f32x16 s = {};
#pragma unroll
        for (int ks = 0; ks < 4; ++ks) {
          int row = ms * 32 + l31;
          bf16x8 ak = *(const bf16x8*)(Kc + row * 64 + (((ks * 2 + lh) ^ (row & 7)) * 8));
          s = __builtin_amdgcn_mfma_f32_32x32x16_bf16(ak, qf[ks], s, 0, 0, 0);
        }
        if (m0 == n0) attn_finish<true>(s, m0, n0, l31, lh, ms, natural, Vc, po);
        else          attn_finish<false>(s, m0, n0, l31, lh, ms, natural, Vc, po);
      }
      __syncthreads();
    }

    // epilogue: pack own accumulators -> xor-swizzled bounce [128 n][64 dl]
    {
      int nrow = wave * 32 + l31;
#pragma unroll
      for (int idl = 0; idl < 2; ++idl) {
#pragma unroll
        for (int g = 0; g < 4; ++g) {
          int dl0 = idl * 32 + g * 8 + lh * 4;
          int addr = nrow * 64 + ((((dl0 >> 3) ^ (nrow & 7)) << 3) | (dl0 & 7));
          ushort4 w;
          w.x = f2bf(po[idl][4 * g + 0]); w.y = f2bf(po[idl][4 * g + 1]);
          w.z = f2bf(po[idl][4 * g + 2]); w.w = f2bf(po[idl][4 * g + 3]);
          *(ushort4*)(bo + addr) = w;
        }
      }
    }
    __syncthreads();
    // coalesced store: Oz[b, t*128+n, hd*64 + c], 64B/thread
    {
      int n = tid >> 1, cc = (tid & 1) * 32;
      __bf16* gdst = Oz + (size_t)(b * 2048 + t * 128 + n) * 512 + hd * 64 + cc;
#pragma unroll
      for (int kk2 = 0; kk2 < 4; ++kk2) {
        int dlb = cc + kk2 * 8;
        int a = n * 64 + (((dlb >> 3) ^ (n & 7)) << 3);
        *(uint4*)(gdst + kk2 * 8) = *(const uint4*)(bo + a);
      }
    }
  }
}

// o_input = u * layer_norm(oa + ob), one block (128 thr) per row
__global__ void k_oinput(const __bf16* __restrict__ oa, const __bf16* __restrict__ ob,
                         const __bf16* __restrict__ u, __bf16* __restrict__ oin) {
  int r = blockIdx.x, t = threadIdx.x;
  ushort4 a4 = ((const ushort4*)(oa + (size_t)r * 512))[t];
  ushort4 b4 = ((const ushort4*)(ob + (size_t)r * 512))[t];
  float a0 = bfu2f(a4.x) + bfu2f(b4.x);
  float a1 = bfu2f(a4.y) + bfu2f(b4.y);
  float a2 = bfu2f(a4.z) + bfu2f(b4.z);
  float a3 = bfu2f(a4.w) + bfu2f(b4.w);
  float s = a0 + a1 + a2 + a3;
  float ss = a0 * a0 + a1 * a1 + a2 * a2 + a3 * a3;
#pragma unroll
  for (int o = 32; o > 0; o >>= 1) { s += __shfl_down(s, o); ss += __shfl_down(ss, o); }
  __shared__ float red[4];
  if ((t & 63) == 0) { red[(t >> 6) * 2] = s; red[(t >> 6) * 2 + 1] = ss; }
  __syncthreads();
  s = red[0] + red[2]; ss = red[1] + red[3];
  float mu = s * (1.0f / 512.0f);
  float var = ss * (1.0f / 512.0f) - mu * mu;
  float rs = rsqrtf(var + 1e-6f);
  ushort4 u4 = ((const ushort4*)(u + (size_t)r * 512))[t];
  ushort4 o4;
  o4.x = f2bf(bfu2f(u4.x) * (a0 - mu) * rs);
  o4.y = f2bf(bfu2f(u4.y) * (a1 - mu) * rs);
  o4.z = f2bf(bfu2f(u4.z) * (a2 - mu) * rs);
  o4.w = f2bf(bfu2f(u4.w) * (a3 - mu) * rs);
  ((ushort4*)(oin + (size_t)r * 512))[t] = o4;
}

// out = o_in @ ow^T + bias + x.  M=8192, N=512, K=512.
// v11: 64x128 tile, 2-PHASE double-buffered LDS (48 KB), one vmcnt(0)+barrier
// per K-step. grid 4x128 = 512 blocks, 3 blocks/CU.
__global__ __launch_bounds__(256, 3) void k_out(
    const __bf16* __restrict__ A, const __bf16* __restrict__ Bt,
    const float* __restrict__ bias, const float* __restrict__ x,
    float* __restrict__ out) {
  __shared__ __bf16 lds[24576];  // 48 KB: A0@0, B0@4096, A1@12288, B1@16384
  int tid = threadIdx.x, wave = tid >> 6, lane = tid & 63;
  int lr = lane & 15, lq = lane >> 4;
  int bn = blockIdx.x, bm = blockIdx.y;
  const __bf16* Ag = A + (size_t)bm * 64 * 512;
  const __bf16* Bg = Bt + (size_t)bn * 128 * 512;
  int wm = (wave >> 1) * 32, wn = (wave & 1) * 64;
  f32x4 acc[2][4] = {};
  // prologue: stage K-step 0 into buf 0
  stage16<8, 2, 7>(Ag, 512, lds, wave, lane);
  stage16<8, 4, 7>(Bg, 512, lds + 4096, wave, lane);
  asm volatile("s_waitcnt vmcnt(0)" ::: "memory");
  __builtin_amdgcn_sched_barrier(0);
  __builtin_amdgcn_s_barrier();
  __builtin_amdgcn_sched_barrier(0);
  int buf = 0;
  for (int t = 0; t < 8; ++t) {
    if (t + 1 < 8) {
      int nb = buf ^ 1;
      stage16<8, 2, 7>(Ag + (t + 1) * 64, 512, lds + nb * 12288, wave, lane);
      stage16<8, 4, 7>(Bg + (t + 1) * 64, 512, lds + nb * 12288 + 4096, wave, lane);
    }
    const __bf16* As = lds + buf * 12288;
    const __bf16* Bs = lds + buf * 12288 + 4096;
#pragma unroll
    for (int kk = 0; kk < 2; ++kk) {
      int b = kk * 4 + lq;
      bf16x8 a[2], bb[4];
#pragma unroll
      for (int i = 0; i < 2; ++i) {
        int row = wm + i * 16 + lr;
        a[i] = *(const bf16x8*)(As + row * 64 + ((b ^ (row & 7)) * 8));
      }
#pragma unroll
      for (int j = 0; j < 4; ++j) {
        int row = wn + j * 16 + lr;
        bb[j] = *(const bf16x8*)(Bs + row * 64 + ((b ^ (row & 7)) * 8));
      }
#pragma unroll
      for (int i = 0; i < 2; ++i)
#pragma unroll
        for (int j = 0; j < 4; ++j)
          acc[i][j] = __builtin_amdgcn_mfma_f32_16x16x32_bf16(a[i], bb[j], acc[i][j], 0, 0, 0);
    }
    asm volatile("s_waitcnt vmcnt(0)" ::: "memory");
    __builtin_amdgcn_sched_barrier(0);
    __builtin_amdgcn_s_barrier();
    __builtin_amdgcn_sched_barrier(0);
    buf ^= 1;
  }
  int cb = bn * 128 + wn;
  int rb0 = bm * 64 + wm + lq * 4;
#pragma unroll
  for (int j = 0; j < 4; ++j) {
    int c = cb + j * 16 + lr;
    float bv = bias[c];
#pragma unroll
    for (int i = 0; i < 2; ++i) {
      int rb = rb0 + i * 16;
#pragma unroll
      for (int rg = 0; rg < 4; ++rg) {
        size_t idx = (size_t)(rb + rg) * 512 + c;
        out[idx] = acc[i][j][rg] + bv + x[idx];
      }
    }
  }
}

extern "C" void kernel_launch(void* const* d_in, const int* in_sizes, int n_in,
                              void* d_out, int out_size, void* d_ws, size_t ws_size,
                              hipStream_t stream) {
  const float* x = (const float*)d_in[0];
  // d_in[1] = attention_mask (deterministic causal tril) -- applied analytically
  const float* uvqk = (const float*)d_in[2];
  const float* ow = (const float*)d_in[3];
  const float* obias = (const float*)d_in[4];
  float* out = (float*)d_out;

  char* w = (char*)d_ws;
  const size_t MB8 = 8u * 1024 * 1024;
  __bf16* nx    = (__bf16*)(w);             // 8 MB
  __bf16* u     = (__bf16*)(w + MB8);       // 8 MB
  __bf16* qn    = (__bf16*)(w + 2 * MB8);   // 8 MB
  __bf16* kn    = (__bf16*)(w + 3 * MB8);   // 8 MB
  __bf16* vt    = (__bf16*)(w + 4 * MB8);   // 8 MB (b, c, n) pre-scaled 1/2048
  __bf16* uvqkT = (__bf16*)(w + 5 * MB8);   // 2 MB
  __bf16* owb   = (__bf16*)(w + 5 * MB8 + 2097152);  // 0.5 MB
  __bf16* Oa    = nx;              // nx dead after k_proj
  __bf16* Ob    = (__bf16*)d_out;  // scratch in d_out (first 8 MB of 16 MB)
  __bf16* o_in  = qn;              // qn dead after k_attn

  k_prep<<<5376, 256, 0, stream>>>(x, nx, ow, owb, uvqk, uvqkT);
  k_proj<<<dim3(16, 64), 256, 0, stream>>>(nx, uvqkT, u, qn, kn, vt);
  k_attn<<<dim3(32, 8, 2), 256, 0, stream>>>(qn, kn, vt, Oa, Ob);
  k_oinput<<<8192, 128, 0, stream>>>(Oa, Ob, u, o_in);
  k_out<<<dim3(4, 128), 256, 0, stream>>>(o_in, owb, obias, x, out);
}